// Round 6
// baseline (267.050 us; speedup 1.0000x reference)
//
#include <hip/hip_runtime.h>

#define B_      2
#define DIM_    256
#define N_      4096
#define HEADS_  8
#define DINNER_ 512

typedef _Float16 half_t;
typedef _Float16 half8  __attribute__((ext_vector_type(8)));
typedef _Float16 half4v __attribute__((ext_vector_type(4)));
typedef _Float16 half2v __attribute__((ext_vector_type(2)));
typedef float    floatx4 __attribute__((ext_vector_type(4)));

#define SCL_    1.4426950408889634f  // log2(e), baked into Q,K
#define SHIFT2_ 20.0f                // fixed softmax shift (log2 domain)

// K=32 granule (Q/K/O tiles, 64kappa x 64mu): halfoff(kappa,mu) =
//   ((kappa>>5)*4 + (mu>>4))*512 + (((kappa>>3)&3)*16 + (mu&15))*8 + (kappa&7)
// V tiles use the K=16 granule: off16(j,dd) =
//   ((j>>4)*4 + (dd>>4))*256 + (((j>>2)&3)*16 + (dd&15))*4 + (j&3)
// perm: [b][slab 0..23][ntile 0..63][4096 halfs]; slab<8: Q, <16: K, else V.

// ---------------- prep: weights -> A-frag fp16; fmap -> xT fp16 ---------------
__global__ __launch_bounds__(256) void prep_all(const float* __restrict__ fmap,
                                                const float* __restrict__ w_qkv,
                                                const float* __restrict__ w_out,
                                                half_t* __restrict__ wqF,
                                                half_t* __restrict__ woF,
                                                half_t* __restrict__ xT) {
    const int t = threadIdx.x, bx = blockIdx.x;
    __shared__ float Tl[64 * 68];
    if (bx < 96) {                 // w_qkv: 96 m-tiles x 256 k
        half_t* dst = wqF + (size_t)bx * 4096;
#pragma unroll
        for (int j = 0; j < 2; ++j) {
            const int cch = j * 256 + t;
            const int o = cch >> 4, m15 = cch & 15;
            const float4 a  = *(const float4*)&w_qkv[(size_t)(bx * 16 + m15) * 256 + o * 8];
            const float4 bb = *(const float4*)&w_qkv[(size_t)(bx * 16 + m15) * 256 + o * 8 + 4];
            half8 hv;
            hv[0] = (half_t)a.x;  hv[1] = (half_t)a.y;  hv[2] = (half_t)a.z;  hv[3] = (half_t)a.w;
            hv[4] = (half_t)bb.x; hv[5] = (half_t)bb.y; hv[6] = (half_t)bb.z; hv[7] = (half_t)bb.w;
            *(half8*)(dst + o * 128 + m15 * 8) = hv;
        }
    } else if (bx < 112) {         // w_out: 16 m-tiles x 512 k
        const int mt = bx - 96;
        half_t* dst = woF + (size_t)mt * 8192;
#pragma unroll
        for (int j = 0; j < 4; ++j) {
            const int cch = j * 256 + t;
            const int o = cch >> 4, m15 = cch & 15;
            const float4 a  = *(const float4*)&w_out[(size_t)(mt * 16 + m15) * 512 + o * 8];
            const float4 bb = *(const float4*)&w_out[(size_t)(mt * 16 + m15) * 512 + o * 8 + 4];
            half8 hv;
            hv[0] = (half_t)a.x;  hv[1] = (half_t)a.y;  hv[2] = (half_t)a.z;  hv[3] = (half_t)a.w;
            hv[4] = (half_t)bb.x; hv[5] = (half_t)bb.y; hv[6] = (half_t)bb.z; hv[7] = (half_t)bb.w;
            *(half8*)(dst + o * 128 + m15 * 8) = hv;
        }
    } else {                       // fmap [k][n] fp32 -> xT [n][k] fp16
        const int idx = bx - 112;
        const int n0 = (idx & 63) * 64, k0 = ((idx >> 6) & 3) * 64, b = idx >> 8;
        {
            const int kk = t >> 2, nq = (t & 3) * 16;
#pragma unroll
            for (int q = 0; q < 4; ++q) {
                float4 v = *(const float4*)&fmap[((size_t)b * DIM_ + k0 + kk) * N_ + n0 + nq + 4 * q];
                *(float4*)&Tl[kk * 68 + nq + 4 * q] = v;
            }
        }
        __syncthreads();
        {
            const int n = t >> 2, ko = (t & 3) * 16;
            half8 h0, h1;
#pragma unroll
            for (int j = 0; j < 8; ++j) h0[j] = (half_t)Tl[(ko + j) * 68 + n];
#pragma unroll
            for (int j = 0; j < 8; ++j) h1[j] = (half_t)Tl[(ko + 8 + j) * 68 + n];
            half_t* dst = xT + ((size_t)b * N_ + n0 + n) * DIM_ + k0 + ko;
            *(half8*)dst       = h0;
            *(half8*)(dst + 8) = h1;
        }
    }
}

// ---------------- GEMM1: qkv projection + fused sq (q^2/k^2) epilogue --------
__global__ __launch_bounds__(256) void mm_qkv_mf(const half_t* __restrict__ wqF,
                                                 const half_t* __restrict__ xT,
                                                 half_t* __restrict__ perm,
                                                 float* __restrict__ sq) {
    const int nt64 = blockIdx.x, by = blockIdx.y, b = blockIdx.z;
    const int t = threadIdx.x, w = t >> 6, L = t & 63, c = L & 15, g = L >> 4;
    const int mt = by * 4 + w;

    const half_t* Ab = wqF + (size_t)mt * 4096;
    const half_t* Bb = xT + ((size_t)b * N_ + nt64 * 64) * DIM_;

    __shared__ __align__(16) char smraw[8192];
    half_t* Vt  = (half_t*)smraw;
    float*  red = (float*)smraw;

    const floatx4 fz = {0.f, 0.f, 0.f, 0.f};
    floatx4 acc[4];
#pragma unroll
    for (int ns = 0; ns < 4; ++ns) acc[ns] = fz;

#pragma unroll
    for (int kc = 0; kc < 8; ++kc) {
        const half8 af = *(const half8*)(Ab + (kc * 4 + g) * 128 + c * 8);
#pragma unroll
        for (int ns = 0; ns < 4; ++ns) {
            const half8 bf = *(const half8*)(Bb + (size_t)(ns * 16 + c) * 256 + kc * 32 + g * 8);
            acc[ns] = __builtin_amdgcn_mfma_f32_16x16x32_f16(af, bf, acc[ns], 0, 0, 0);
        }
    }

    half_t* dst = perm + (((size_t)(b * 24 + by) * 64 + nt64) << 12);
    if (by < 16) {
        // Q/K scaled by log2e: kappa = d = 16w+4g+i, mu = 16ns+c
        float part[4];
#pragma unroll
        for (int ns = 0; ns < 4; ++ns) {
            half_t hv[4];
#pragma unroll
            for (int i = 0; i < 4; ++i) hv[i] = (half_t)(acc[ns][i] * SCL_);
            const int off = ((w >> 1) * 4 + ns) * 512 + (((2 * w + (g >> 1)) & 3) * 16 + c) * 8 + 4 * (g & 1);
            half2v p0, p1;
            p0[0] = hv[0]; p0[1] = hv[1];
            p1[0] = hv[2]; p1[1] = hv[3];
            *(half2v*)(dst + off)     = p0;
            *(half2v*)(dst + off + 2) = p1;
            float s = 0.f;
#pragma unroll
            for (int i = 0; i < 4; ++i) { const float f = (float)hv[i]; s = fmaf(f, f, s); }
            part[ns] = s;
        }
#pragma unroll
        for (int ns = 0; ns < 4; ++ns)
            red[(ns * 16 + (w * 4 + g)) * 17 + c] = part[ns];
        __syncthreads();
        if (t < 64) {
            const int ns = t >> 4, cc = t & 15;
            float s = 0.f;
#pragma unroll
            for (int wg = 0; wg < 16; ++wg) s += red[(ns * 16 + wg) * 17 + cc];
            const int tens = by >> 3, hh = by & 7;
            sq[((size_t)(tens * 16 + b * 8 + hh)) * N_ + nt64 * 64 + ns * 16 + cc] = s;
        }
    } else {
        // V: j = 16ns+c (spatial), dd = 16w+4g+i -> K=16 granule via LDS bounce
#pragma unroll
        for (int ns = 0; ns < 4; ++ns)
#pragma unroll
            for (int i = 0; i < 4; ++i)
                Vt[(ns * 4 + w) * 256 + ((c >> 2) * 16 + 4 * g + i) * 4 + (c & 3)] = (half_t)acc[ns][i];
        __syncthreads();
#pragma unroll
        for (int j = 0; j < 2; ++j)
            *(half8*)(dst + t * 16 + j * 8) = *(half8*)(Vt + t * 16 + j * 8);
    }
}

// ---------------- fused distance-attention, split-K x2, fixed-shift ----------
// grid.x = 64: qb = bx&31 (128 queries), kh = bx>>5 (K-halves). Unnormalized
// O-half (fp16, frag layout) + l-half (f32) out; combined in mm_out (fixed
// shift => partials add with no rescale).
__global__ __launch_bounds__(512) void attn_mfma(const half_t* __restrict__ perm,
                                                 const float* __restrict__ sq,
                                                 half_t* __restrict__ oh,
                                                 float* __restrict__ lbuf) {
    const int bx = blockIdx.x;
    const int qb = bx & 31, kh = bx >> 5;
    const int h = blockIdx.y, b = blockIdx.z;
    const int bh = b * HEADS_ + h;

    const half_t* Qb = perm + ((size_t)(b * 24 + h) << 18);
    const half_t* Kb = perm + ((size_t)(b * 24 + 8 + h) << 18);
    const half_t* Vb = perm + ((size_t)(b * 24 + 16 + h) << 18);
    const float* q2a = sq + (size_t)bh * N_;
    const float* k2a = sq + (size_t)(16 + bh) * N_;

    __shared__ __align__(16) half_t Kl[2][4096];
    __shared__ __align__(16) half_t Vl[2][4096];

    const int t = threadIdx.x, w = t >> 6, L = t & 63, c = L & 15, g = L >> 4;
    const floatx4 fz = {0.f, 0.f, 0.f, 0.f};

    const half_t* Qt = Qb + ((size_t)(qb * 2 + (w >> 2)) << 12);
    const half8 bq0 = *(const half8*)(Qt + (0 * 4 + (w & 3)) * 512 + L * 8);
    const half8 bq1 = *(const half8*)(Qt + (1 * 4 + (w & 3)) * 512 + L * 8);
    const float q2l = q2a[qb * 128 + 16 * w + c];

    half4v aone;   // ones row m=0 for l-MFMA
    {
        const half_t ov = (c == 0) ? (half_t)1.0f : (half_t)0.0f;
        aone[0] = ov; aone[1] = ov; aone[2] = ov; aone[3] = ov;
    }

    floatx4 O[4];
    floatx4 lac = fz;
#pragma unroll
    for (int dt = 0; dt < 4; ++dt) O[dt] = fz;

    const int kt0 = kh * 32;
    half8 rk = *(const half8*)(Kb + ((size_t)kt0 << 12) + t * 8);
    half8 rv = *(const half8*)(Vb + ((size_t)kt0 << 12) + t * 8);

    for (int it = 0; it < 32; ++it) {
        const int kt = kt0 + it;
        const int buf = it & 1;
        *(half8*)(&Kl[buf][t * 8]) = rk;
        *(half8*)(&Vl[buf][t * 8]) = rv;
        if (it < 31) {
            rk = *(const half8*)(Kb + ((size_t)(kt + 1) << 12) + t * 8);
            rv = *(const half8*)(Vb + ((size_t)(kt + 1) << 12) + t * 8);
        }
        __syncthreads();

#pragma unroll
        for (int nt = 0; nt < 4; ++nt) {
            const half8 ak0 = *(const half8*)(&Kl[buf][(0 * 4 + nt) * 512 + L * 8]);
            const half8 ak1 = *(const half8*)(&Kl[buf][(1 * 4 + nt) * 512 + L * 8]);
            floatx4 S = __builtin_amdgcn_mfma_f32_16x16x32_f16(ak0, bq0, fz, 0, 0, 0);
            S = __builtin_amdgcn_mfma_f32_16x16x32_f16(ak1, bq1, S, 0, 0, 0);
            const float4 k2v = *(const float4*)&k2a[kt * 64 + 16 * nt + 4 * g];
            const float p0 = __builtin_amdgcn_exp2f(
                __builtin_amdgcn_sqrtf(fmaxf(fmaf(S[0], -2.0f, q2l + k2v.x), 0.0f)) - SHIFT2_);
            const float p1 = __builtin_amdgcn_exp2f(
                __builtin_amdgcn_sqrtf(fmaxf(fmaf(S[1], -2.0f, q2l + k2v.y), 0.0f)) - SHIFT2_);
            const float p2 = __builtin_amdgcn_exp2f(
                __builtin_amdgcn_sqrtf(fmaxf(fmaf(S[2], -2.0f, q2l + k2v.z), 0.0f)) - SHIFT2_);
            const float p3 = __builtin_amdgcn_exp2f(
                __builtin_amdgcn_sqrtf(fmaxf(fmaf(S[3], -2.0f, q2l + k2v.w), 0.0f)) - SHIFT2_);
            const half2v lo = __builtin_bit_cast(half2v, __builtin_amdgcn_cvt_pkrtz(p0, p1));
            const half2v hi = __builtin_bit_cast(half2v, __builtin_amdgcn_cvt_pkrtz(p2, p3));
            half4v bp;
            bp[0] = lo[0]; bp[1] = lo[1]; bp[2] = hi[0]; bp[3] = hi[1];

            lac = __builtin_amdgcn_mfma_f32_16x16x16f16(aone, bp, lac, 0, 0, 0);
#pragma unroll
            for (int dt = 0; dt < 4; ++dt) {
                const half4v av = *(const half4v*)(&Vl[buf][(nt * 4 + dt) * 256 + L * 4]);
                O[dt] = __builtin_amdgcn_mfma_f32_16x16x16f16(av, bp, O[dt], 0, 0, 0);
            }
        }
    }

    // write unnormalized O-half (fp16, K=32 granule: kappa=dd, mu=spatial)
    const int ntile = qb * 2 + (w >> 2);
    half_t* dst = oh + (size_t)kh * 4194304 + (((size_t)bh * 64 + ntile) << 12);
#pragma unroll
    for (int dt = 0; dt < 4; ++dt) {
        const int off = ((dt >> 1) * 4 + (w & 3)) * 512 + (((2 * dt + (g >> 1)) & 3) * 16 + c) * 8 + 4 * (g & 1);
        const half2v p0 = __builtin_bit_cast(half2v, __builtin_amdgcn_cvt_pkrtz(O[dt][0], O[dt][1]));
        const half2v p1 = __builtin_bit_cast(half2v, __builtin_amdgcn_cvt_pkrtz(O[dt][2], O[dt][3]));
        *(half2v*)(dst + off)     = p0;
        *(half2v*)(dst + off + 2) = p1;
    }
    // l-half: lanes 0..15 hold l for q = lane (row 0 of lac)
    if (L < 16)
        lbuf[(size_t)kh * 65536 + (size_t)bh * N_ + qb * 128 + w * 16 + L] = lac[0];
}

// ---------------- GEMM3: out projection + split-K combine inline -------------
__global__ __launch_bounds__(256) void mm_out_mf(const half_t* __restrict__ woF,
                                                 const half_t* __restrict__ oh,
                                                 const float* __restrict__ lbuf,
                                                 float* __restrict__ out) {
    const int nt64 = blockIdx.x, mb = blockIdx.y, b = blockIdx.z;
    const int t = threadIdx.x, w = t >> 6, L = t & 63, c = L & 15, g = L >> 4;
    const int mt = mb * 4 + w;

    const half_t* Ab = woF + (size_t)mt * 8192;
    const floatx4 fz = {0.f, 0.f, 0.f, 0.f};
    floatx4 O4[4];
#pragma unroll
    for (int ns = 0; ns < 4; ++ns) O4[ns] = fz;

#pragma unroll
    for (int h = 0; h < 8; ++h) {
        const int bh = b * 8 + h;
        const size_t toff = (((size_t)bh * 64 + nt64) << 12);
        const half_t* B0 = oh + toff;
        const half_t* B1 = oh + 4194304 + toff;
        floatx4 acc[4];
#pragma unroll
        for (int ns = 0; ns < 4; ++ns) acc[ns] = fz;
#pragma unroll
        for (int c2 = 0; c2 < 2; ++c2) {
            const half8 af = *(const half8*)(Ab + (h * 8 + c2 * 4 + g) * 128 + c * 8);
#pragma unroll
            for (int ns = 0; ns < 4; ++ns) {
                const half8 b0 = *(const half8*)(B0 + (c2 * 4 + ns) * 512 + L * 8);
                const half8 b1 = *(const half8*)(B1 + (c2 * 4 + ns) * 512 + L * 8);
                const half8 s = b0 + b1;   // fixed-shift partials add directly
                acc[ns] = __builtin_amdgcn_mfma_f32_16x16x32_f16(af, s, acc[ns], 0, 0, 0);
            }
        }
#pragma unroll
        for (int ns = 0; ns < 4; ++ns) {
            const size_t li = (size_t)bh * N_ + nt64 * 64 + ns * 16 + c;
            const float l = lbuf[li] + lbuf[65536 + li];
            const float inv = __builtin_amdgcn_rcpf(l);
#pragma unroll
            for (int i = 0; i < 4; ++i) O4[ns][i] = fmaf(acc[ns][i], inv, O4[ns][i]);
        }
    }

    float* Cg = out + ((size_t)b * DIM_ + mt * 16) * N_ + nt64 * 64;
#pragma unroll
    for (int ns = 0; ns < 4; ++ns)
#pragma unroll
        for (int i = 0; i < 4; ++i)
            Cg[(size_t)(4 * g + i) * N_ + ns * 16 + c] = O4[ns][i];
}

extern "C" void kernel_launch(void* const* d_in, const int* in_sizes, int n_in,
                              void* d_out, int out_size, void* d_ws, size_t ws_size,
                              hipStream_t stream) {
    const float* fmap  = (const float*)d_in[0];
    const float* w_qkv = (const float*)d_in[1];
    const float* w_out = (const float*)d_in[2];
    float* out = (float*)d_out;

    char* ws = (char*)d_ws;
    half_t* perm = (half_t*)ws;                       // 25,165,824 B
    half_t* oh   = (half_t*)(ws + 25165824);          // 2 x 8,388,608 B
    float*  lbuf = (float*) (ws + 41943040);          // 2 x   262,144 B
    float*  sq   = (float*) (ws + 42467328);          //       524,288 B
    half_t* xT   = (half_t*)(ws + 42991616);          //     4,194,304 B
    half_t* wqF  = (half_t*)(ws + 47185920);          //       786,432 B
    half_t* woF  = (half_t*)(ws + 47972352);          //       262,144 B

    prep_all <<<624, 256, 0, stream>>>(fmap, w_qkv, w_out, wqF, woF, xT);
    mm_qkv_mf<<<dim3(64, 24, 2), 256, 0, stream>>>(wqF, xT, perm, sq);
    attn_mfma<<<dim3(64, 8, 2), 512, 0, stream>>>(perm, sq, oh, lbuf);
    mm_out_mf<<<dim3(64, 4, 2), 256, 0, stream>>>(woF, oh, lbuf, out);
}

// Round 7
// 261.644 us; speedup vs baseline: 1.0207x; 1.0207x over previous
//
#include <hip/hip_runtime.h>

#define B_      2
#define DIM_    256
#define N_      4096
#define HEADS_  8
#define DINNER_ 512

typedef _Float16 half_t;
typedef _Float16 half8  __attribute__((ext_vector_type(8)));
typedef _Float16 half4v __attribute__((ext_vector_type(4)));
typedef _Float16 half2v __attribute__((ext_vector_type(2)));
typedef float    floatx4 __attribute__((ext_vector_type(4)));

#define SCL_    1.4426950408889634f  // log2(e), baked into Q,K
#define SHIFT2_ 20.0f                // fixed softmax shift (log2 domain)

// K=32 granule (Q/K/O tiles, 64kappa x 64mu): halfoff(kappa,mu) =
//   ((kappa>>5)*4 + (mu>>4))*512 + (((kappa>>3)&3)*16 + (mu&15))*8 + (kappa&7)
// V tiles use the K=16 granule: off16(j,dd) =
//   ((j>>4)*4 + (dd>>4))*256 + (((j>>2)&3)*16 + (dd&15))*4 + (j&3)
// perm: [b][slab 0..23][ntile 0..63][4096 halfs]; slab<8: Q, <16: K, else V.

// ---------------- prep: weights -> A-frag fp16; fmap -> xT fp16 ---------------
__global__ __launch_bounds__(256) void prep_all(const float* __restrict__ fmap,
                                                const float* __restrict__ w_qkv,
                                                const float* __restrict__ w_out,
                                                half_t* __restrict__ wqF,
                                                half_t* __restrict__ woF,
                                                half_t* __restrict__ xT) {
    const int t = threadIdx.x, bx = blockIdx.x;
    __shared__ float Tl[64 * 68];
    if (bx < 96) {                 // w_qkv: 96 m-tiles x 256 k
        half_t* dst = wqF + (size_t)bx * 4096;
#pragma unroll
        for (int j = 0; j < 2; ++j) {
            const int cch = j * 256 + t;
            const int o = cch >> 4, m15 = cch & 15;
            const float4 a  = *(const float4*)&w_qkv[(size_t)(bx * 16 + m15) * 256 + o * 8];
            const float4 bb = *(const float4*)&w_qkv[(size_t)(bx * 16 + m15) * 256 + o * 8 + 4];
            half8 hv;
            hv[0] = (half_t)a.x;  hv[1] = (half_t)a.y;  hv[2] = (half_t)a.z;  hv[3] = (half_t)a.w;
            hv[4] = (half_t)bb.x; hv[5] = (half_t)bb.y; hv[6] = (half_t)bb.z; hv[7] = (half_t)bb.w;
            *(half8*)(dst + o * 128 + m15 * 8) = hv;
        }
    } else if (bx < 112) {         // w_out: 16 m-tiles x 512 k
        const int mt = bx - 96;
        half_t* dst = woF + (size_t)mt * 8192;
#pragma unroll
        for (int j = 0; j < 4; ++j) {
            const int cch = j * 256 + t;
            const int o = cch >> 4, m15 = cch & 15;
            const float4 a  = *(const float4*)&w_out[(size_t)(mt * 16 + m15) * 512 + o * 8];
            const float4 bb = *(const float4*)&w_out[(size_t)(mt * 16 + m15) * 512 + o * 8 + 4];
            half8 hv;
            hv[0] = (half_t)a.x;  hv[1] = (half_t)a.y;  hv[2] = (half_t)a.z;  hv[3] = (half_t)a.w;
            hv[4] = (half_t)bb.x; hv[5] = (half_t)bb.y; hv[6] = (half_t)bb.z; hv[7] = (half_t)bb.w;
            *(half8*)(dst + o * 128 + m15 * 8) = hv;
        }
    } else {                       // fmap [k][n] fp32 -> xT [n][k] fp16
        const int idx = bx - 112;
        const int n0 = (idx & 63) * 64, k0 = ((idx >> 6) & 3) * 64, b = idx >> 8;
        {
            const int kk = t >> 2, nq = (t & 3) * 16;
#pragma unroll
            for (int q = 0; q < 4; ++q) {
                float4 v = *(const float4*)&fmap[((size_t)b * DIM_ + k0 + kk) * N_ + n0 + nq + 4 * q];
                *(float4*)&Tl[kk * 68 + nq + 4 * q] = v;
            }
        }
        __syncthreads();
        {
            const int n = t >> 2, ko = (t & 3) * 16;
            half8 h0, h1;
#pragma unroll
            for (int j = 0; j < 8; ++j) h0[j] = (half_t)Tl[(ko + j) * 68 + n];
#pragma unroll
            for (int j = 0; j < 8; ++j) h1[j] = (half_t)Tl[(ko + 8 + j) * 68 + n];
            half_t* dst = xT + ((size_t)b * N_ + n0 + n) * DIM_ + k0 + ko;
            *(half8*)dst       = h0;
            *(half8*)(dst + 8) = h1;
        }
    }
}

// ---------------- GEMM1: qkv projection, fp16 MFMA, LDS-free core ------------
__global__ __launch_bounds__(256) void mm_qkv_mf(const half_t* __restrict__ wqF,
                                                 const half_t* __restrict__ xT,
                                                 half_t* __restrict__ perm) {
    const int nt64 = blockIdx.x, by = blockIdx.y, b = blockIdx.z;
    const int t = threadIdx.x, w = t >> 6, L = t & 63, c = L & 15, g = L >> 4;
    const int mt = by * 4 + w;

    const half_t* Ab = wqF + (size_t)mt * 4096;
    const half_t* Bb = xT + ((size_t)b * N_ + nt64 * 64) * DIM_;

    __shared__ half_t Vt[4096];

    const floatx4 fz = {0.f, 0.f, 0.f, 0.f};
    floatx4 acc[4];
#pragma unroll
    for (int ns = 0; ns < 4; ++ns) acc[ns] = fz;

#pragma unroll
    for (int kc = 0; kc < 8; ++kc) {
        const half8 af = *(const half8*)(Ab + (kc * 4 + g) * 128 + c * 8);
#pragma unroll
        for (int ns = 0; ns < 4; ++ns) {
            const half8 bf = *(const half8*)(Bb + (size_t)(ns * 16 + c) * 256 + kc * 32 + g * 8);
            acc[ns] = __builtin_amdgcn_mfma_f32_16x16x32_f16(af, bf, acc[ns], 0, 0, 0);
        }
    }

    half_t* dst = perm + (((size_t)(b * 24 + by) * 64 + nt64) << 12);
    if (by < 16) {
        // Q/K scaled by log2e: kappa = d = 16w+4g+i, mu = 16ns+c
#pragma unroll
        for (int ns = 0; ns < 4; ++ns) {
            const int off = ((w >> 1) * 4 + ns) * 512 + (((2 * w + (g >> 1)) & 3) * 16 + c) * 8 + 4 * (g & 1);
            half2v p0, p1;
            p0[0] = (half_t)(acc[ns][0] * SCL_); p0[1] = (half_t)(acc[ns][1] * SCL_);
            p1[0] = (half_t)(acc[ns][2] * SCL_); p1[1] = (half_t)(acc[ns][3] * SCL_);
            *(half2v*)(dst + off)     = p0;
            *(half2v*)(dst + off + 2) = p1;
        }
    } else {
        // V: j = 16ns+c (spatial), dd = 16w+4g+i -> K=16 granule via LDS bounce
#pragma unroll
        for (int ns = 0; ns < 4; ++ns)
#pragma unroll
            for (int i = 0; i < 4; ++i)
                Vt[(ns * 4 + w) * 256 + ((c >> 2) * 16 + 4 * g + i) * 4 + (c & 3)] = (half_t)acc[ns][i];
        __syncthreads();
#pragma unroll
        for (int j = 0; j < 2; ++j)
            *(half8*)(dst + t * 16 + j * 8) = *(half8*)(Vt + t * 16 + j * 8);
    }
}

// ---------------- q'^2 / k'^2 from the quantized, scaled fp16 values ---------
__global__ __launch_bounds__(256) void sq_kernel(const half_t* __restrict__ perm,
                                                 float* __restrict__ sq) {
    const int bh = blockIdx.y, tens = blockIdx.z;  // 0=Q, 1=K
    const int b = bh >> 3, h = bh & 7;
    const int nt = blockIdx.x * 4 + (threadIdx.x >> 6);
    const half_t* tile = perm + (((size_t)(b * 24 + tens * 8 + h) * 64 + nt) << 12);
    const int cc = threadIdx.x & 63;
    const int cp = cc >> 4, cl = cc & 15;
    float acc = 0.f;
#pragma unroll
    for (int sg = 0; sg < 8; ++sg) {
        const half8 v = *(const half8*)(tile + ((sg >> 2) * 4 + cp) * 512 + ((sg & 3) * 16 + cl) * 8);
#pragma unroll
        for (int j = 0; j < 8; ++j) { const float f = (float)v[j]; acc = fmaf(f, f, acc); }
    }
    sq[((size_t)tens * 16 + bh) * N_ + nt * 64 + cc] = acc;
}

// ---------------- fused distance-attention, 2 q-subtiles/wave, split-K x2 ----
// Block: 512 thr, 256 queries; wave w owns q-subtiles 2w, 2w+1 (perm tile
// qb*4 + (w>>1), planes p0/p1). Same ak/av/k2 LDS reads feed both subtiles ->
// DS cycles per query halved vs one-subtile. Fixed-shift softmax: split-K
// partials (unnormalized O fp16 + l f32) add with no rescale in mm_out.
__global__ __launch_bounds__(512) void attn_mfma(const half_t* __restrict__ perm,
                                                 const float* __restrict__ sq,
                                                 half_t* __restrict__ oh,
                                                 float* __restrict__ lbuf) {
    const int bx = blockIdx.x;
    const int qb = bx & 15, kh = bx >> 4;
    const int h = blockIdx.y, b = blockIdx.z;
    const int bh = b * HEADS_ + h;

    const half_t* Qb = perm + ((size_t)(b * 24 + h) << 18);
    const half_t* Kb = perm + ((size_t)(b * 24 + 8 + h) << 18);
    const half_t* Vb = perm + ((size_t)(b * 24 + 16 + h) << 18);
    const float* q2a = sq + (size_t)bh * N_;
    const float* k2a = sq + (size_t)(16 + bh) * N_;

    __shared__ __align__(16) half_t Kl[2][4096];
    __shared__ __align__(16) half_t Vl[2][4096];
    __shared__ __align__(16) float  k2l[2048];

    const int t = threadIdx.x, w = t >> 6, L = t & 63, c = L & 15, g = L >> 4;
    const floatx4 fz = {0.f, 0.f, 0.f, 0.f};

    // stage this K-half's k2 (8 KB) once
    *(float4*)&k2l[t * 4] = *(const float4*)&k2a[kh * 2048 + t * 4];

    // persistent Q B-frags for 2 subtiles
    const int tl = w >> 1;                  // perm tile local 0..3
    const int p0 = (w & 1) * 2, p1 = p0 + 1;
    const half_t* Qt = Qb + ((size_t)(qb * 4 + tl) << 12);
    const half8 bq0a = *(const half8*)(Qt + (0 * 4 + p0) * 512 + L * 8);
    const half8 bq1a = *(const half8*)(Qt + (1 * 4 + p0) * 512 + L * 8);
    const half8 bq0b = *(const half8*)(Qt + (0 * 4 + p1) * 512 + L * 8);
    const half8 bq1b = *(const half8*)(Qt + (1 * 4 + p1) * 512 + L * 8);
    const float q2la = q2a[qb * 256 + 64 * tl + 16 * p0 + c];
    const float q2lb = q2a[qb * 256 + 64 * tl + 16 * p1 + c];

    half4v aone;   // ones row m=0 for l-MFMA
    {
        const half_t ov = (c == 0) ? (half_t)1.0f : (half_t)0.0f;
        aone[0] = ov; aone[1] = ov; aone[2] = ov; aone[3] = ov;
    }

    floatx4 Oa[4], Ob[4];
    floatx4 laca = fz, lacb = fz;
#pragma unroll
    for (int dt = 0; dt < 4; ++dt) { Oa[dt] = fz; Ob[dt] = fz; }

    const int kt0 = kh * 32;
    half8 rk = *(const half8*)(Kb + ((size_t)kt0 << 12) + t * 8);
    half8 rv = *(const half8*)(Vb + ((size_t)kt0 << 12) + t * 8);

    for (int it = 0; it < 32; ++it) {
        const int buf = it & 1;
        __syncthreads();                    // prior reads of buf done (2-deep)
        *(half8*)(&Kl[buf][t * 8]) = rk;
        *(half8*)(&Vl[buf][t * 8]) = rv;
        if (it < 31) {
            rk = *(const half8*)(Kb + ((size_t)(kt0 + it + 1) << 12) + t * 8);
            rv = *(const half8*)(Vb + ((size_t)(kt0 + it + 1) << 12) + t * 8);
        }
        __syncthreads();

#pragma unroll
        for (int nt = 0; nt < 4; ++nt) {
            const half8 ak0 = *(const half8*)(&Kl[buf][(0 * 4 + nt) * 512 + L * 8]);
            const half8 ak1 = *(const half8*)(&Kl[buf][(1 * 4 + nt) * 512 + L * 8]);
            floatx4 Sa = __builtin_amdgcn_mfma_f32_16x16x32_f16(ak0, bq0a, fz, 0, 0, 0);
            Sa = __builtin_amdgcn_mfma_f32_16x16x32_f16(ak1, bq1a, Sa, 0, 0, 0);
            floatx4 Sb = __builtin_amdgcn_mfma_f32_16x16x32_f16(ak0, bq0b, fz, 0, 0, 0);
            Sb = __builtin_amdgcn_mfma_f32_16x16x32_f16(ak1, bq1b, Sb, 0, 0, 0);
            const float4 k2v = *(const float4*)&k2l[it * 64 + 16 * nt + 4 * g];

            float pa[4], pb[4];
            const float k2arr[4] = {k2v.x, k2v.y, k2v.z, k2v.w};
#pragma unroll
            for (int i = 0; i < 4; ++i) {
                pa[i] = __builtin_amdgcn_exp2f(
                    __builtin_amdgcn_sqrtf(fmaxf(fmaf(Sa[i], -2.0f, q2la + k2arr[i]), 0.0f)) - SHIFT2_);
                pb[i] = __builtin_amdgcn_exp2f(
                    __builtin_amdgcn_sqrtf(fmaxf(fmaf(Sb[i], -2.0f, q2lb + k2arr[i]), 0.0f)) - SHIFT2_);
            }
            half4v bpa, bpb;
            {
                const half2v a0 = __builtin_bit_cast(half2v, __builtin_amdgcn_cvt_pkrtz(pa[0], pa[1]));
                const half2v a1 = __builtin_bit_cast(half2v, __builtin_amdgcn_cvt_pkrtz(pa[2], pa[3]));
                bpa[0] = a0[0]; bpa[1] = a0[1]; bpa[2] = a1[0]; bpa[3] = a1[1];
                const half2v b0 = __builtin_bit_cast(half2v, __builtin_amdgcn_cvt_pkrtz(pb[0], pb[1]));
                const half2v b1 = __builtin_bit_cast(half2v, __builtin_amdgcn_cvt_pkrtz(pb[2], pb[3]));
                bpb[0] = b0[0]; bpb[1] = b0[1]; bpb[2] = b1[0]; bpb[3] = b1[1];
            }

            laca = __builtin_amdgcn_mfma_f32_16x16x16f16(aone, bpa, laca, 0, 0, 0);
            lacb = __builtin_amdgcn_mfma_f32_16x16x16f16(aone, bpb, lacb, 0, 0, 0);
#pragma unroll
            for (int dt = 0; dt < 4; ++dt) {
                const half4v av = *(const half4v*)(&Vl[buf][(nt * 4 + dt) * 256 + L * 4]);
                Oa[dt] = __builtin_amdgcn_mfma_f32_16x16x16f16(av, bpa, Oa[dt], 0, 0, 0);
                Ob[dt] = __builtin_amdgcn_mfma_f32_16x16x16f16(av, bpb, Ob[dt], 0, 0, 0);
            }
        }
    }

    // write unnormalized O-halves (fp16, K=32 granule: kappa=dd, mu=16*plane+c)
    const int ntile = qb * 4 + tl;
    half_t* dst = oh + (size_t)kh * 4194304 + (((size_t)bh * 64 + ntile) << 12);
#pragma unroll
    for (int dt = 0; dt < 4; ++dt) {
        const int obase = ((dt >> 1) * 4) * 512 + (((2 * dt + (g >> 1)) & 3) * 16 + c) * 8 + 4 * (g & 1);
        const half2v a0 = __builtin_bit_cast(half2v, __builtin_amdgcn_cvt_pkrtz(Oa[dt][0], Oa[dt][1]));
        const half2v a1 = __builtin_bit_cast(half2v, __builtin_amdgcn_cvt_pkrtz(Oa[dt][2], Oa[dt][3]));
        *(half2v*)(dst + obase + p0 * 512)     = a0;
        *(half2v*)(dst + obase + p0 * 512 + 2) = a1;
        const half2v b0 = __builtin_bit_cast(half2v, __builtin_amdgcn_cvt_pkrtz(Ob[dt][0], Ob[dt][1]));
        const half2v b1 = __builtin_bit_cast(half2v, __builtin_amdgcn_cvt_pkrtz(Ob[dt][2], Ob[dt][3]));
        *(half2v*)(dst + obase + p1 * 512)     = b0;
        *(half2v*)(dst + obase + p1 * 512 + 2) = b1;
    }
    // l: row m=0 of lac -> lanes 0..15, reg 0
    if (L < 16) {
        const size_t lb0 = (size_t)kh * 65536 + (size_t)bh * N_ + qb * 256 + 64 * tl;
        lbuf[lb0 + 16 * p0 + L] = laca[0];
        lbuf[lb0 + 16 * p1 + L] = lacb[0];
    }
}

// ---------------- GEMM3: out projection + split-K combine inline -------------
__global__ __launch_bounds__(256) void mm_out_mf(const half_t* __restrict__ woF,
                                                 const half_t* __restrict__ oh,
                                                 const float* __restrict__ lbuf,
                                                 float* __restrict__ out) {
    const int nt64 = blockIdx.x, mb = blockIdx.y, b = blockIdx.z;
    const int t = threadIdx.x, w = t >> 6, L = t & 63, c = L & 15, g = L >> 4;
    const int mt = mb * 4 + w;

    const half_t* Ab = woF + (size_t)mt * 8192;
    const floatx4 fz = {0.f, 0.f, 0.f, 0.f};
    floatx4 O4[4];
#pragma unroll
    for (int ns = 0; ns < 4; ++ns) O4[ns] = fz;

#pragma unroll
    for (int h = 0; h < 8; ++h) {
        const int bh = b * 8 + h;
        const size_t toff = (((size_t)bh * 64 + nt64) << 12);
        const half_t* B0 = oh + toff;
        const half_t* B1 = oh + 4194304 + toff;
        floatx4 acc[4];
#pragma unroll
        for (int ns = 0; ns < 4; ++ns) acc[ns] = fz;
#pragma unroll
        for (int c2 = 0; c2 < 2; ++c2) {
            const half8 af = *(const half8*)(Ab + (h * 8 + c2 * 4 + g) * 128 + c * 8);
#pragma unroll
            for (int ns = 0; ns < 4; ++ns) {
                const half8 b0 = *(const half8*)(B0 + (c2 * 4 + ns) * 512 + L * 8);
                const half8 b1 = *(const half8*)(B1 + (c2 * 4 + ns) * 512 + L * 8);
                const half8 s = b0 + b1;   // fixed-shift partials add directly
                acc[ns] = __builtin_amdgcn_mfma_f32_16x16x32_f16(af, s, acc[ns], 0, 0, 0);
            }
        }
#pragma unroll
        for (int ns = 0; ns < 4; ++ns) {
            const size_t li = (size_t)bh * N_ + nt64 * 64 + ns * 16 + c;
            const float l = lbuf[li] + lbuf[65536 + li];
            const float inv = __builtin_amdgcn_rcpf(l);
#pragma unroll
            for (int i = 0; i < 4; ++i) O4[ns][i] = fmaf(acc[ns][i], inv, O4[ns][i]);
        }
    }

    float* Cg = out + ((size_t)b * DIM_ + mt * 16) * N_ + nt64 * 64;
#pragma unroll
    for (int ns = 0; ns < 4; ++ns)
#pragma unroll
        for (int i = 0; i < 4; ++i)
            Cg[(size_t)(4 * g + i) * N_ + ns * 16 + c] = O4[ns][i];
}

extern "C" void kernel_launch(void* const* d_in, const int* in_sizes, int n_in,
                              void* d_out, int out_size, void* d_ws, size_t ws_size,
                              hipStream_t stream) {
    const float* fmap  = (const float*)d_in[0];
    const float* w_qkv = (const float*)d_in[1];
    const float* w_out = (const float*)d_in[2];
    float* out = (float*)d_out;

    char* ws = (char*)d_ws;
    half_t* perm = (half_t*)ws;                       // 25,165,824 B
    half_t* oh   = (half_t*)(ws + 25165824);          // 2 x 8,388,608 B
    float*  lbuf = (float*) (ws + 41943040);          // 2 x   262,144 B
    float*  sq   = (float*) (ws + 42467328);          //       524,288 B
    half_t* xT   = (half_t*)(ws + 42991616);          //     4,194,304 B
    half_t* wqF  = (half_t*)(ws + 47185920);          //       786,432 B
    half_t* woF  = (half_t*)(ws + 47972352);          //       262,144 B

    prep_all <<<624, 256, 0, stream>>>(fmap, w_qkv, w_out, wqF, woF, xT);
    mm_qkv_mf<<<dim3(64, 24, 2), 256, 0, stream>>>(wqF, xT, perm);
    sq_kernel<<<dim3(16, 16, 2), 256, 0, stream>>>(perm, sq);
    attn_mfma<<<dim3(32, 8, 2), 512, 0, stream>>>(perm, sq, oh, lbuf);
    mm_out_mf<<<dim3(64, 4, 2), 256, 0, stream>>>(woF, oh, lbuf, out);
}

// Round 8
// 214.405 us; speedup vs baseline: 1.2455x; 1.2203x over previous
//
#include <hip/hip_runtime.h>

#define B_      2
#define DIM_    256
#define N_      4096
#define HEADS_  8
#define DINNER_ 512

typedef _Float16 half_t;
typedef _Float16 half8  __attribute__((ext_vector_type(8)));
typedef _Float16 half4v __attribute__((ext_vector_type(4)));
typedef _Float16 half2v __attribute__((ext_vector_type(2)));
typedef float    floatx4 __attribute__((ext_vector_type(4)));

#define SCL_    1.4426950408889634f  // log2(e), baked into Q,K
#define SHIFT2_ 20.0f                // fixed softmax shift (log2 domain)

// K=32 granule (64kappa x 64mu): halfoff(kappa,mu) =
//   ((kappa>>5)*4 + (mu>>4))*512 + (((kappa>>3)&3)*16 + (mu&15))*8 + (kappa&7)
// V tiles use the K=16 granule: off16(j,dd) =
//   ((j>>4)*4 + (dd>>4))*256 + (((j>>2)&3)*16 + (dd&15))*4 + (j&3)
// perm: [b][slab 0..23][ntile 0..63][4096 halfs]; slab<8: Q, <16: K, else V.
// xTg:  [b][ntile 0..63][kslab 0..3][4096 halfs]  (fmap in granule layout)

// ---------------- prep: weights -> A-frag fp16; fmap -> xTg granule fp16 -----
__global__ __launch_bounds__(256) void prep_all(const float* __restrict__ fmap,
                                                const float* __restrict__ w_qkv,
                                                const float* __restrict__ w_out,
                                                half_t* __restrict__ wqF,
                                                half_t* __restrict__ woF,
                                                half_t* __restrict__ xTg) {
    const int t = threadIdx.x, bx = blockIdx.x;
    __shared__ float Tl[64 * 68];
    if (bx < 96) {                 // w_qkv: 96 m-tiles x 256 k
        half_t* dst = wqF + (size_t)bx * 4096;
#pragma unroll
        for (int j = 0; j < 2; ++j) {
            const int cch = j * 256 + t;
            const int o = cch >> 4, m15 = cch & 15;
            const float4 a  = *(const float4*)&w_qkv[(size_t)(bx * 16 + m15) * 256 + o * 8];
            const float4 bb = *(const float4*)&w_qkv[(size_t)(bx * 16 + m15) * 256 + o * 8 + 4];
            half8 hv;
            hv[0] = (half_t)a.x;  hv[1] = (half_t)a.y;  hv[2] = (half_t)a.z;  hv[3] = (half_t)a.w;
            hv[4] = (half_t)bb.x; hv[5] = (half_t)bb.y; hv[6] = (half_t)bb.z; hv[7] = (half_t)bb.w;
            *(half8*)(dst + o * 128 + m15 * 8) = hv;
        }
    } else if (bx < 112) {         // w_out: 16 m-tiles x 512 k
        const int mt = bx - 96;
        half_t* dst = woF + (size_t)mt * 8192;
#pragma unroll
        for (int j = 0; j < 4; ++j) {
            const int cch = j * 256 + t;
            const int o = cch >> 4, m15 = cch & 15;
            const float4 a  = *(const float4*)&w_out[(size_t)(mt * 16 + m15) * 512 + o * 8];
            const float4 bb = *(const float4*)&w_out[(size_t)(mt * 16 + m15) * 512 + o * 8 + 4];
            half8 hv;
            hv[0] = (half_t)a.x;  hv[1] = (half_t)a.y;  hv[2] = (half_t)a.z;  hv[3] = (half_t)a.w;
            hv[4] = (half_t)bb.x; hv[5] = (half_t)bb.y; hv[6] = (half_t)bb.z; hv[7] = (half_t)bb.w;
            *(half8*)(dst + o * 128 + m15 * 8) = hv;
        }
    } else {                       // fmap [k][n] fp32 -> xTg granule fp16
        const int idx = bx - 112;
        const int n0 = (idx & 63) * 64, k0 = ((idx >> 6) & 3) * 64, b = idx >> 8;
        {
            const int kk = t >> 2, nq = (t & 3) * 16;
#pragma unroll
            for (int q = 0; q < 4; ++q) {
                float4 v = *(const float4*)&fmap[((size_t)b * DIM_ + k0 + kk) * N_ + n0 + nq + 4 * q];
                *(float4*)&Tl[kk * 68 + nq + 4 * q] = v;
            }
        }
        __syncthreads();
        {
            const int n = t >> 2, ko = (t & 3) * 16;   // kappa_local = ko..ko+15
            half8 h0, h1;
#pragma unroll
            for (int j = 0; j < 8; ++j) h0[j] = (half_t)Tl[(ko + j) * 68 + n];
#pragma unroll
            for (int j = 0; j < 8; ++j) h1[j] = (half_t)Tl[(ko + 8 + j) * 68 + n];
            half_t* dst = xTg + (((size_t)b * 64 + (n0 >> 6)) * 4 + (k0 >> 6)) * 4096;
            const int o0 = ((ko >> 5) * 4 + (n >> 4)) * 512 + (((ko >> 3) & 3) * 16 + (n & 15)) * 8;
            const int k8 = ko + 8;
            const int o1 = ((k8 >> 5) * 4 + (n >> 4)) * 512 + (((k8 >> 3) & 3) * 16 + (n & 15)) * 8;
            *(half8*)(dst + o0) = h0;
            *(half8*)(dst + o1) = h1;
        }
    }
}

// ---------------- GEMM1: qkv projection, fp16 MFMA, LDS-free, coalesced B ----
__global__ __launch_bounds__(256) void mm_qkv_mf(const half_t* __restrict__ wqF,
                                                 const half_t* __restrict__ xTg,
                                                 half_t* __restrict__ perm) {
    const int nt64 = blockIdx.x, by = blockIdx.y, b = blockIdx.z;
    const int t = threadIdx.x, w = t >> 6, L = t & 63, c = L & 15, g = L >> 4;
    const int mt = by * 4 + w;

    const half_t* Ab = wqF + (size_t)mt * 4096;
    const half_t* Bb = xTg + (((size_t)b * 64 + nt64) * 4) * 4096;

    __shared__ half_t Vt[4096];

    const floatx4 fz = {0.f, 0.f, 0.f, 0.f};
    floatx4 acc[4];
#pragma unroll
    for (int ns = 0; ns < 4; ++ns) acc[ns] = fz;

#pragma unroll
    for (int kc = 0; kc < 8; ++kc) {
        const half8 af = *(const half8*)(Ab + (kc * 4 + g) * 128 + c * 8);
        const half_t* Bs = Bb + (kc >> 1) * 4096 + (kc & 1) * 2048;
#pragma unroll
        for (int ns = 0; ns < 4; ++ns) {
            const half8 bf = *(const half8*)(Bs + ns * 512 + L * 8);   // linear, coalesced
            acc[ns] = __builtin_amdgcn_mfma_f32_16x16x32_f16(af, bf, acc[ns], 0, 0, 0);
        }
    }

    half_t* dst = perm + (((size_t)(b * 24 + by) * 64 + nt64) << 12);
    if (by < 16) {
        // Q/K scaled by log2e: kappa = d = 16w+4g+i, mu = 16ns+c
#pragma unroll
        for (int ns = 0; ns < 4; ++ns) {
            const int off = ((w >> 1) * 4 + ns) * 512 + (((2 * w + (g >> 1)) & 3) * 16 + c) * 8 + 4 * (g & 1);
            half2v p0, p1;
            p0[0] = (half_t)(acc[ns][0] * SCL_); p0[1] = (half_t)(acc[ns][1] * SCL_);
            p1[0] = (half_t)(acc[ns][2] * SCL_); p1[1] = (half_t)(acc[ns][3] * SCL_);
            *(half2v*)(dst + off)     = p0;
            *(half2v*)(dst + off + 2) = p1;
        }
    } else {
        // V: j = 16ns+c (spatial), dd = 16w+4g+i -> K=16 granule via LDS bounce
#pragma unroll
        for (int ns = 0; ns < 4; ++ns)
#pragma unroll
            for (int i = 0; i < 4; ++i)
                Vt[(ns * 4 + w) * 256 + ((c >> 2) * 16 + 4 * g + i) * 4 + (c & 3)] = (half_t)acc[ns][i];
        __syncthreads();
#pragma unroll
        for (int j = 0; j < 2; ++j)
            *(half8*)(dst + t * 16 + j * 8) = *(half8*)(Vt + t * 16 + j * 8);
    }
}

// ---------------- q'^2 / k'^2 from the quantized, scaled fp16 values ---------
__global__ __launch_bounds__(256) void sq_kernel(const half_t* __restrict__ perm,
                                                 float* __restrict__ sq) {
    const int bh = blockIdx.y, tens = blockIdx.z;  // 0=Q, 1=K
    const int b = bh >> 3, h = bh & 7;
    const int nt = blockIdx.x * 4 + (threadIdx.x >> 6);
    const half_t* tile = perm + (((size_t)(b * 24 + tens * 8 + h) * 64 + nt) << 12);
    const int cc = threadIdx.x & 63;
    const int cp = cc >> 4, cl = cc & 15;
    float acc = 0.f;
#pragma unroll
    for (int sg = 0; sg < 8; ++sg) {
        const half8 v = *(const half8*)(tile + ((sg >> 2) * 4 + cp) * 512 + ((sg & 3) * 16 + cl) * 8);
#pragma unroll
        for (int j = 0; j < 8; ++j) { const float f = (float)v[j]; acc = fmaf(f, f, acc); }
    }
    sq[((size_t)tens * 16 + bh) * N_ + nt * 64 + cc] = acc;
}

// ---------------- fused distance-attention, no-drain pipeline ----------------
// Single barrier/iter via raw "s_waitcnt lgkmcnt(0); s_barrier" (vmcnt stays
// outstanding across the barrier); K/V prefetch issued AFTER the barrier so it
// overlaps the whole compute phase. 2-buffer LDS; 2 q-subtiles/wave; split-K x2.
__global__ __launch_bounds__(512) void attn_mfma(const half_t* __restrict__ perm,
                                                 const float* __restrict__ sq,
                                                 half_t* __restrict__ oh,
                                                 float* __restrict__ lbuf) {
    const int bx = blockIdx.x;
    const int qb = bx & 15, kh = bx >> 4;
    const int h = blockIdx.y, b = blockIdx.z;
    const int bh = b * HEADS_ + h;

    const half_t* Qb = perm + ((size_t)(b * 24 + h) << 18);
    const half_t* Kb = perm + ((size_t)(b * 24 + 8 + h) << 18);
    const half_t* Vb = perm + ((size_t)(b * 24 + 16 + h) << 18);
    const float* q2a = sq + (size_t)bh * N_;
    const float* k2a = sq + (size_t)(16 + bh) * N_;

    __shared__ __align__(16) half_t Kl[2][4096];
    __shared__ __align__(16) half_t Vl[2][4096];
    __shared__ __align__(16) float  k2l[2048];

    const int t = threadIdx.x, w = t >> 6, L = t & 63, c = L & 15, g = L >> 4;
    const floatx4 fz = {0.f, 0.f, 0.f, 0.f};

    // stage this K-half's k2 (8 KB) once; visible after iter-0 barrier
    *(float4*)&k2l[t * 4] = *(const float4*)&k2a[kh * 2048 + t * 4];

    // persistent Q B-frags for 2 subtiles
    const int tl = w >> 1;
    const int p0 = (w & 1) * 2, p1 = p0 + 1;
    const half_t* Qt = Qb + ((size_t)(qb * 4 + tl) << 12);
    const half8 bq0a = *(const half8*)(Qt + (0 * 4 + p0) * 512 + L * 8);
    const half8 bq1a = *(const half8*)(Qt + (1 * 4 + p0) * 512 + L * 8);
    const half8 bq0b = *(const half8*)(Qt + (0 * 4 + p1) * 512 + L * 8);
    const half8 bq1b = *(const half8*)(Qt + (1 * 4 + p1) * 512 + L * 8);
    const float q2la = q2a[qb * 256 + 64 * tl + 16 * p0 + c];
    const float q2lb = q2a[qb * 256 + 64 * tl + 16 * p1 + c];

    half4v aone;   // ones row m=0 for l-MFMA
    {
        const half_t ov = (c == 0) ? (half_t)1.0f : (half_t)0.0f;
        aone[0] = ov; aone[1] = ov; aone[2] = ov; aone[3] = ov;
    }

    floatx4 Oa[4], Ob[4];
    floatx4 laca = fz, lacb = fz;
#pragma unroll
    for (int dt = 0; dt < 4; ++dt) { Oa[dt] = fz; Ob[dt] = fz; }

    const int kt0 = kh * 32;
    half8 rk = *(const half8*)(Kb + ((size_t)kt0 << 12) + t * 8);
    half8 rv = *(const half8*)(Vb + ((size_t)kt0 << 12) + t * 8);

    for (int it = 0; it < 32; ++it) {
        const int buf = it & 1;
        *(half8*)(&Kl[buf][t * 8]) = rk;     // waits vmcnt for rk/rv data dep only
        *(half8*)(&Vl[buf][t * 8]) = rv;
        // LDS-only barrier: vmcnt (prefetch) stays outstanding across it.
        asm volatile("s_waitcnt lgkmcnt(0)\n\ts_barrier" ::: "memory");
        if (it < 31) {                        // prefetch overlaps compute below
            rk = *(const half8*)(Kb + ((size_t)(kt0 + it + 1) << 12) + t * 8);
            rv = *(const half8*)(Vb + ((size_t)(kt0 + it + 1) << 12) + t * 8);
        }

#pragma unroll
        for (int nt = 0; nt < 4; ++nt) {
            const half8 ak0 = *(const half8*)(&Kl[buf][(0 * 4 + nt) * 512 + L * 8]);
            const half8 ak1 = *(const half8*)(&Kl[buf][(1 * 4 + nt) * 512 + L * 8]);
            floatx4 Sa = __builtin_amdgcn_mfma_f32_16x16x32_f16(ak0, bq0a, fz, 0, 0, 0);
            Sa = __builtin_amdgcn_mfma_f32_16x16x32_f16(ak1, bq1a, Sa, 0, 0, 0);
            floatx4 Sb = __builtin_amdgcn_mfma_f32_16x16x32_f16(ak0, bq0b, fz, 0, 0, 0);
            Sb = __builtin_amdgcn_mfma_f32_16x16x32_f16(ak1, bq1b, Sb, 0, 0, 0);
            const float4 k2v = *(const float4*)&k2l[it * 64 + 16 * nt + 4 * g];

            float pa[4], pb[4];
            const float k2arr[4] = {k2v.x, k2v.y, k2v.z, k2v.w};
#pragma unroll
            for (int i = 0; i < 4; ++i) {
                pa[i] = __builtin_amdgcn_exp2f(
                    __builtin_amdgcn_sqrtf(fmaxf(fmaf(Sa[i], -2.0f, q2la + k2arr[i]), 0.0f)) - SHIFT2_);
                pb[i] = __builtin_amdgcn_exp2f(
                    __builtin_amdgcn_sqrtf(fmaxf(fmaf(Sb[i], -2.0f, q2lb + k2arr[i]), 0.0f)) - SHIFT2_);
            }
            half4v bpa, bpb;
            {
                const half2v a0 = __builtin_bit_cast(half2v, __builtin_amdgcn_cvt_pkrtz(pa[0], pa[1]));
                const half2v a1 = __builtin_bit_cast(half2v, __builtin_amdgcn_cvt_pkrtz(pa[2], pa[3]));
                bpa[0] = a0[0]; bpa[1] = a0[1]; bpa[2] = a1[0]; bpa[3] = a1[1];
                const half2v b0 = __builtin_bit_cast(half2v, __builtin_amdgcn_cvt_pkrtz(pb[0], pb[1]));
                const half2v b1 = __builtin_bit_cast(half2v, __builtin_amdgcn_cvt_pkrtz(pb[2], pb[3]));
                bpb[0] = b0[0]; bpb[1] = b0[1]; bpb[2] = b1[0]; bpb[3] = b1[1];
            }

            laca = __builtin_amdgcn_mfma_f32_16x16x16f16(aone, bpa, laca, 0, 0, 0);
            lacb = __builtin_amdgcn_mfma_f32_16x16x16f16(aone, bpb, lacb, 0, 0, 0);
#pragma unroll
            for (int dt = 0; dt < 4; ++dt) {
                const half4v av = *(const half4v*)(&Vl[buf][(nt * 4 + dt) * 256 + L * 4]);
                Oa[dt] = __builtin_amdgcn_mfma_f32_16x16x16f16(av, bpa, Oa[dt], 0, 0, 0);
                Ob[dt] = __builtin_amdgcn_mfma_f32_16x16x16f16(av, bpb, Ob[dt], 0, 0, 0);
            }
        }
    }

    // write unnormalized O-halves (fp16, K=32 granule: kappa=dd, mu=16*plane+c)
    const int ntile = qb * 4 + tl;
    half_t* dst = oh + (size_t)kh * 4194304 + (((size_t)bh * 64 + ntile) << 12);
#pragma unroll
    for (int dt = 0; dt < 4; ++dt) {
        const int obase = ((dt >> 1) * 4) * 512 + (((2 * dt + (g >> 1)) & 3) * 16 + c) * 8 + 4 * (g & 1);
        const half2v a0 = __builtin_bit_cast(half2v, __builtin_amdgcn_cvt_pkrtz(Oa[dt][0], Oa[dt][1]));
        const half2v a1 = __builtin_bit_cast(half2v, __builtin_amdgcn_cvt_pkrtz(Oa[dt][2], Oa[dt][3]));
        *(half2v*)(dst + obase + p0 * 512)     = a0;
        *(half2v*)(dst + obase + p0 * 512 + 2) = a1;
        const half2v b0 = __builtin_bit_cast(half2v, __builtin_amdgcn_cvt_pkrtz(Ob[dt][0], Ob[dt][1]));
        const half2v b1 = __builtin_bit_cast(half2v, __builtin_amdgcn_cvt_pkrtz(Ob[dt][2], Ob[dt][3]));
        *(half2v*)(dst + obase + p1 * 512)     = b0;
        *(half2v*)(dst + obase + p1 * 512 + 2) = b1;
    }
    // l: row m=0 of lac -> lanes 0..15, reg 0
    if (L < 16) {
        const size_t lb0 = (size_t)kh * 65536 + (size_t)bh * N_ + qb * 256 + 64 * tl;
        lbuf[lb0 + 16 * p0 + L] = laca[0];
        lbuf[lb0 + 16 * p1 + L] = lacb[0];
    }
}

// ---------------- GEMM3: out projection + split-K combine inline -------------
__global__ __launch_bounds__(256) void mm_out_mf(const half_t* __restrict__ woF,
                                                 const half_t* __restrict__ oh,
                                                 const float* __restrict__ lbuf,
                                                 float* __restrict__ out) {
    const int nt64 = blockIdx.x, mb = blockIdx.y, b = blockIdx.z;
    const int t = threadIdx.x, w = t >> 6, L = t & 63, c = L & 15, g = L >> 4;
    const int mt = mb * 4 + w;

    const half_t* Ab = woF + (size_t)mt * 8192;
    const floatx4 fz = {0.f, 0.f, 0.f, 0.f};
    floatx4 O4[4];
#pragma unroll
    for (int ns = 0; ns < 4; ++ns) O4[ns] = fz;

#pragma unroll
    for (int h = 0; h < 8; ++h) {
        const int bh = b * 8 + h;
        const size_t toff = (((size_t)bh * 64 + nt64) << 12);
        const half_t* B0 = oh + toff;
        const half_t* B1 = oh + 4194304 + toff;
        floatx4 acc[4];
#pragma unroll
        for (int ns = 0; ns < 4; ++ns) acc[ns] = fz;
#pragma unroll
        for (int c2 = 0; c2 < 2; ++c2) {
            const half8 af = *(const half8*)(Ab + (h * 8 + c2 * 4 + g) * 128 + c * 8);
#pragma unroll
            for (int ns = 0; ns < 4; ++ns) {
                const half8 b0 = *(const half8*)(B0 + (c2 * 4 + ns) * 512 + L * 8);
                const half8 b1 = *(const half8*)(B1 + (c2 * 4 + ns) * 512 + L * 8);
                const half8 s = b0 + b1;   // fixed-shift partials add directly
                acc[ns] = __builtin_amdgcn_mfma_f32_16x16x32_f16(af, s, acc[ns], 0, 0, 0);
            }
        }
#pragma unroll
        for (int ns = 0; ns < 4; ++ns) {
            const size_t li = (size_t)bh * N_ + nt64 * 64 + ns * 16 + c;
            const float l = lbuf[li] + lbuf[65536 + li];
            const float inv = __builtin_amdgcn_rcpf(l);
#pragma unroll
            for (int i = 0; i < 4; ++i) O4[ns][i] = fmaf(acc[ns][i], inv, O4[ns][i]);
        }
    }

    float* Cg = out + ((size_t)b * DIM_ + mt * 16) * N_ + nt64 * 64;
#pragma unroll
    for (int ns = 0; ns < 4; ++ns)
#pragma unroll
        for (int i = 0; i < 4; ++i)
            Cg[(size_t)(4 * g + i) * N_ + ns * 16 + c] = O4[ns][i];
}

extern "C" void kernel_launch(void* const* d_in, const int* in_sizes, int n_in,
                              void* d_out, int out_size, void* d_ws, size_t ws_size,
                              hipStream_t stream) {
    const float* fmap  = (const float*)d_in[0];
    const float* w_qkv = (const float*)d_in[1];
    const float* w_out = (const float*)d_in[2];
    float* out = (float*)d_out;

    char* ws = (char*)d_ws;
    half_t* perm = (half_t*)ws;                       // 25,165,824 B
    half_t* oh   = (half_t*)(ws + 25165824);          // 2 x 8,388,608 B
    float*  lbuf = (float*) (ws + 41943040);          // 2 x   262,144 B
    float*  sq   = (float*) (ws + 42467328);          //       524,288 B
    half_t* xTg  = (half_t*)(ws + 42991616);          //     4,194,304 B
    half_t* wqF  = (half_t*)(ws + 47185920);          //       786,432 B
    half_t* woF  = (half_t*)(ws + 47972352);          //       262,144 B

    prep_all <<<624, 256, 0, stream>>>(fmap, w_qkv, w_out, wqF, woF, xTg);
    mm_qkv_mf<<<dim3(64, 24, 2), 256, 0, stream>>>(wqF, xTg, perm);
    sq_kernel<<<dim3(16, 16, 2), 256, 0, stream>>>(perm, sq);
    attn_mfma<<<dim3(32, 8, 2), 512, 0, stream>>>(perm, sq, oh, lbuf);
    mm_out_mf<<<dim3(64, 4, 2), 256, 0, stream>>>(woF, oh, lbuf, out);
}

// Round 9
// 211.429 us; speedup vs baseline: 1.2631x; 1.0141x over previous
//
#include <hip/hip_runtime.h>

#define B_      2
#define DIM_    256
#define N_      4096
#define HEADS_  8
#define DINNER_ 512

typedef _Float16 half_t;
typedef _Float16 half8  __attribute__((ext_vector_type(8)));
typedef _Float16 half4v __attribute__((ext_vector_type(4)));
typedef _Float16 half2v __attribute__((ext_vector_type(2)));
typedef float    floatx4 __attribute__((ext_vector_type(4)));

#define SCL_    1.4426950408889634f  // log2(e), baked into Q,K
#define SHIFT2_ 20.0f                // fixed softmax shift (log2 domain)

// K=32 granule (64kappa x 64mu): halfoff(kappa,mu) =
//   ((kappa>>5)*4 + (mu>>4))*512 + (((kappa>>3)&3)*16 + (mu&15))*8 + (kappa&7)
// V tiles use the K=16 granule: off16(j,dd) =
//   ((j>>4)*4 + (dd>>4))*256 + (((j>>2)&3)*16 + (dd&15))*4 + (j&3)
// perm: [b][slab 0..23][ntile 0..63][4096 halfs]; slab<8: Q, <16: K, else V.
// xTg:  [b][ntile 0..63][kslab 0..3][4096 halfs]  (fmap in granule layout)

// ---------------- prep: weights -> A-frag fp16; fmap -> xTg granule fp16 -----
__global__ __launch_bounds__(256) void prep_all(const float* __restrict__ fmap,
                                                const float* __restrict__ w_qkv,
                                                const float* __restrict__ w_out,
                                                half_t* __restrict__ wqF,
                                                half_t* __restrict__ woF,
                                                half_t* __restrict__ xTg) {
    const int t = threadIdx.x, bx = blockIdx.x;
    __shared__ float Tl[64 * 68];
    if (bx < 96) {                 // w_qkv: 96 m-tiles x 256 k
        half_t* dst = wqF + (size_t)bx * 4096;
#pragma unroll
        for (int j = 0; j < 2; ++j) {
            const int cch = j * 256 + t;
            const int o = cch >> 4, m15 = cch & 15;
            const float4 a  = *(const float4*)&w_qkv[(size_t)(bx * 16 + m15) * 256 + o * 8];
            const float4 bb = *(const float4*)&w_qkv[(size_t)(bx * 16 + m15) * 256 + o * 8 + 4];
            half8 hv;
            hv[0] = (half_t)a.x;  hv[1] = (half_t)a.y;  hv[2] = (half_t)a.z;  hv[3] = (half_t)a.w;
            hv[4] = (half_t)bb.x; hv[5] = (half_t)bb.y; hv[6] = (half_t)bb.z; hv[7] = (half_t)bb.w;
            *(half8*)(dst + o * 128 + m15 * 8) = hv;
        }
    } else if (bx < 112) {         // w_out: 16 m-tiles x 512 k
        const int mt = bx - 96;
        half_t* dst = woF + (size_t)mt * 8192;
#pragma unroll
        for (int j = 0; j < 4; ++j) {
            const int cch = j * 256 + t;
            const int o = cch >> 4, m15 = cch & 15;
            const float4 a  = *(const float4*)&w_out[(size_t)(mt * 16 + m15) * 512 + o * 8];
            const float4 bb = *(const float4*)&w_out[(size_t)(mt * 16 + m15) * 512 + o * 8 + 4];
            half8 hv;
            hv[0] = (half_t)a.x;  hv[1] = (half_t)a.y;  hv[2] = (half_t)a.z;  hv[3] = (half_t)a.w;
            hv[4] = (half_t)bb.x; hv[5] = (half_t)bb.y; hv[6] = (half_t)bb.z; hv[7] = (half_t)bb.w;
            *(half8*)(dst + o * 128 + m15 * 8) = hv;
        }
    } else {                       // fmap [k][n] fp32 -> xTg granule fp16
        const int idx = bx - 112;
        const int n0 = (idx & 63) * 64, k0 = ((idx >> 6) & 3) * 64, b = idx >> 8;
        {
            const int kk = t >> 2, nq = (t & 3) * 16;
#pragma unroll
            for (int q = 0; q < 4; ++q) {
                float4 v = *(const float4*)&fmap[((size_t)b * DIM_ + k0 + kk) * N_ + n0 + nq + 4 * q];
                *(float4*)&Tl[kk * 68 + nq + 4 * q] = v;
            }
        }
        __syncthreads();
        {
            const int n = t >> 2, ko = (t & 3) * 16;   // kappa_local = ko..ko+15
            half8 h0, h1;
#pragma unroll
            for (int j = 0; j < 8; ++j) h0[j] = (half_t)Tl[(ko + j) * 68 + n];
#pragma unroll
            for (int j = 0; j < 8; ++j) h1[j] = (half_t)Tl[(ko + 8 + j) * 68 + n];
            half_t* dst = xTg + (((size_t)b * 64 + (n0 >> 6)) * 4 + (k0 >> 6)) * 4096;
            const int o0 = ((ko >> 5) * 4 + (n >> 4)) * 512 + (((ko >> 3) & 3) * 16 + (n & 15)) * 8;
            const int k8 = ko + 8;
            const int o1 = ((k8 >> 5) * 4 + (n >> 4)) * 512 + (((k8 >> 3) & 3) * 16 + (n & 15)) * 8;
            *(half8*)(dst + o0) = h0;
            *(half8*)(dst + o1) = h1;
        }
    }
}

// ---------------- GEMM1: qkv projection + fused sq; coalesced LDS-bounce -----
__global__ __launch_bounds__(256) void mm_qkv_mf(const half_t* __restrict__ wqF,
                                                 const half_t* __restrict__ xTg,
                                                 half_t* __restrict__ perm,
                                                 float* __restrict__ sq) {
    const int nt64 = blockIdx.x, by = blockIdx.y, b = blockIdx.z;
    const int t = threadIdx.x, w = t >> 6, L = t & 63, c = L & 15, g = L >> 4;
    const int mt = by * 4 + w;

    const half_t* Ab = wqF + (size_t)mt * 4096;
    const half_t* Bb = xTg + (((size_t)b * 64 + nt64) * 4) * 4096;

    __shared__ __align__(16) char smraw[8192 + 4352];
    half_t* VtH = (half_t*)smraw;                 // 4096-half granule bounce
    float*  red = (float*)(smraw + 8192);         // sq reduction, stride 17

    const floatx4 fz = {0.f, 0.f, 0.f, 0.f};
    floatx4 acc[4];
#pragma unroll
    for (int ns = 0; ns < 4; ++ns) acc[ns] = fz;

#pragma unroll
    for (int kc = 0; kc < 8; ++kc) {
        const half8 af = *(const half8*)(Ab + (kc * 4 + g) * 128 + c * 8);
        const half_t* Bs = Bb + (kc >> 1) * 4096 + (kc & 1) * 2048;
#pragma unroll
        for (int ns = 0; ns < 4; ++ns) {
            const half8 bf = *(const half8*)(Bs + ns * 512 + L * 8);   // linear, coalesced
            acc[ns] = __builtin_amdgcn_mfma_f32_16x16x32_f16(af, bf, acc[ns], 0, 0, 0);
        }
    }

    half_t* dst = perm + (((size_t)(b * 24 + by) * 64 + nt64) << 12);
    if (by < 16) {
        // Q/K scaled by log2e: kappa = d = 16w+4g+i, mu = 16ns+c.
        // Granule tile assembled in LDS, stored with 2 b128/thread; squares
        // accumulated register-side for the fused sq epilogue.
        float part[4];
#pragma unroll
        for (int ns = 0; ns < 4; ++ns) {
            half_t hv[4];
            float s = 0.f;
#pragma unroll
            for (int i = 0; i < 4; ++i) {
                hv[i] = (half_t)(acc[ns][i] * SCL_);
                const float f = (float)hv[i];
                s = fmaf(f, f, s);
            }
            part[ns] = s;
            const int off = ((w >> 1) * 4 + ns) * 512 + (((2 * w + (g >> 1)) & 3) * 16 + c) * 8 + 4 * (g & 1);
            half2v p0, p1;
            p0[0] = hv[0]; p0[1] = hv[1];
            p1[0] = hv[2]; p1[1] = hv[3];
            *(half2v*)(VtH + off)     = p0;
            *(half2v*)(VtH + off + 2) = p1;
        }
#pragma unroll
        for (int ns = 0; ns < 4; ++ns)
            red[(ns * 16 + (w * 4 + g)) * 17 + c] = part[ns];
        __syncthreads();
#pragma unroll
        for (int j = 0; j < 2; ++j)
            *(half8*)(dst + t * 16 + j * 8) = *(half8*)(VtH + t * 16 + j * 8);
        if (t < 64) {
            const int ns = t >> 4, cc = t & 15;
            float s = 0.f;
#pragma unroll
            for (int wg = 0; wg < 16; ++wg) s += red[(ns * 16 + wg) * 17 + cc];
            const int tens = by >> 3, hh = by & 7;
            sq[((size_t)(tens * 16 + b * 8 + hh)) * N_ + nt64 * 64 + ns * 16 + cc] = s;
        }
    } else {
        // V: j = 16ns+c (spatial), dd = 16w+4g+i -> K=16 granule via LDS bounce
#pragma unroll
        for (int ns = 0; ns < 4; ++ns)
#pragma unroll
            for (int i = 0; i < 4; ++i)
                VtH[(ns * 4 + w) * 256 + ((c >> 2) * 16 + 4 * g + i) * 4 + (c & 3)] = (half_t)acc[ns][i];
        __syncthreads();
#pragma unroll
        for (int j = 0; j < 2; ++j)
            *(half8*)(dst + t * 16 + j * 8) = *(half8*)(VtH + t * 16 + j * 8);
    }
}

// ---------------- fused distance-attention, no-drain pipeline ----------------
// Single barrier/iter via "s_waitcnt lgkmcnt(0); s_barrier" (vmcnt stays
// outstanding); K/V prefetch issued AFTER the barrier overlaps compute.
// 2-buffer LDS; 2 q-subtiles/wave; split-K x2; fixed-shift softmax.
__global__ __launch_bounds__(512) void attn_mfma(const half_t* __restrict__ perm,
                                                 const float* __restrict__ sq,
                                                 half_t* __restrict__ oh,
                                                 float* __restrict__ lbuf) {
    const int bx = blockIdx.x;
    const int qb = bx & 15, kh = bx >> 4;
    const int h = blockIdx.y, b = blockIdx.z;
    const int bh = b * HEADS_ + h;

    const half_t* Qb = perm + ((size_t)(b * 24 + h) << 18);
    const half_t* Kb = perm + ((size_t)(b * 24 + 8 + h) << 18);
    const half_t* Vb = perm + ((size_t)(b * 24 + 16 + h) << 18);
    const float* q2a = sq + (size_t)bh * N_;
    const float* k2a = sq + (size_t)(16 + bh) * N_;

    __shared__ __align__(16) half_t Kl[2][4096];
    __shared__ __align__(16) half_t Vl[2][4096];
    __shared__ __align__(16) float  k2l[2048];

    const int t = threadIdx.x, w = t >> 6, L = t & 63, c = L & 15, g = L >> 4;
    const floatx4 fz = {0.f, 0.f, 0.f, 0.f};

    // stage this K-half's k2 (8 KB) once; visible after iter-0 barrier
    *(float4*)&k2l[t * 4] = *(const float4*)&k2a[kh * 2048 + t * 4];

    // persistent Q B-frags for 2 subtiles
    const int tl = w >> 1;
    const int p0 = (w & 1) * 2, p1 = p0 + 1;
    const half_t* Qt = Qb + ((size_t)(qb * 4 + tl) << 12);
    const half8 bq0a = *(const half8*)(Qt + (0 * 4 + p0) * 512 + L * 8);
    const half8 bq1a = *(const half8*)(Qt + (1 * 4 + p0) * 512 + L * 8);
    const half8 bq0b = *(const half8*)(Qt + (0 * 4 + p1) * 512 + L * 8);
    const half8 bq1b = *(const half8*)(Qt + (1 * 4 + p1) * 512 + L * 8);
    const float q2la = q2a[qb * 256 + 64 * tl + 16 * p0 + c];
    const float q2lb = q2a[qb * 256 + 64 * tl + 16 * p1 + c];

    half4v aone;   // ones row m=0 for l-MFMA
    {
        const half_t ov = (c == 0) ? (half_t)1.0f : (half_t)0.0f;
        aone[0] = ov; aone[1] = ov; aone[2] = ov; aone[3] = ov;
    }

    floatx4 Oa[4], Ob[4];
    floatx4 laca = fz, lacb = fz;
#pragma unroll
    for (int dt = 0; dt < 4; ++dt) { Oa[dt] = fz; Ob[dt] = fz; }

    const int kt0 = kh * 32;
    half8 rk = *(const half8*)(Kb + ((size_t)kt0 << 12) + t * 8);
    half8 rv = *(const half8*)(Vb + ((size_t)kt0 << 12) + t * 8);

    for (int it = 0; it < 32; ++it) {
        const int buf = it & 1;
        *(half8*)(&Kl[buf][t * 8]) = rk;     // waits vmcnt for rk/rv data dep only
        *(half8*)(&Vl[buf][t * 8]) = rv;
        // LDS-only barrier: vmcnt (prefetch) stays outstanding across it.
        asm volatile("s_waitcnt lgkmcnt(0)\n\ts_barrier" ::: "memory");
        if (it < 31) {                        // prefetch overlaps compute below
            rk = *(const half8*)(Kb + ((size_t)(kt0 + it + 1) << 12) + t * 8);
            rv = *(const half8*)(Vb + ((size_t)(kt0 + it + 1) << 12) + t * 8);
        }

#pragma unroll
        for (int nt = 0; nt < 4; ++nt) {
            const half8 ak0 = *(const half8*)(&Kl[buf][(0 * 4 + nt) * 512 + L * 8]);
            const half8 ak1 = *(const half8*)(&Kl[buf][(1 * 4 + nt) * 512 + L * 8]);
            floatx4 Sa = __builtin_amdgcn_mfma_f32_16x16x32_f16(ak0, bq0a, fz, 0, 0, 0);
            Sa = __builtin_amdgcn_mfma_f32_16x16x32_f16(ak1, bq1a, Sa, 0, 0, 0);
            floatx4 Sb = __builtin_amdgcn_mfma_f32_16x16x32_f16(ak0, bq0b, fz, 0, 0, 0);
            Sb = __builtin_amdgcn_mfma_f32_16x16x32_f16(ak1, bq1b, Sb, 0, 0, 0);
            const float4 k2v = *(const float4*)&k2l[it * 64 + 16 * nt + 4 * g];

            float pa[4], pb[4];
            const float k2arr[4] = {k2v.x, k2v.y, k2v.z, k2v.w};
#pragma unroll
            for (int i = 0; i < 4; ++i) {
                // |d2| instead of max(d2,0): abs is a free src modifier on sqrt
                pa[i] = __builtin_amdgcn_exp2f(
                    __builtin_amdgcn_sqrtf(__builtin_fabsf(fmaf(Sa[i], -2.0f, q2la + k2arr[i]))) - SHIFT2_);
                pb[i] = __builtin_amdgcn_exp2f(
                    __builtin_amdgcn_sqrtf(__builtin_fabsf(fmaf(Sb[i], -2.0f, q2lb + k2arr[i]))) - SHIFT2_);
            }
            half4v bpa, bpb;
            {
                const half2v a0 = __builtin_bit_cast(half2v, __builtin_amdgcn_cvt_pkrtz(pa[0], pa[1]));
                const half2v a1 = __builtin_bit_cast(half2v, __builtin_amdgcn_cvt_pkrtz(pa[2], pa[3]));
                bpa[0] = a0[0]; bpa[1] = a0[1]; bpa[2] = a1[0]; bpa[3] = a1[1];
                const half2v b0 = __builtin_bit_cast(half2v, __builtin_amdgcn_cvt_pkrtz(pb[0], pb[1]));
                const half2v b1 = __builtin_bit_cast(half2v, __builtin_amdgcn_cvt_pkrtz(pb[2], pb[3]));
                bpb[0] = b0[0]; bpb[1] = b0[1]; bpb[2] = b1[0]; bpb[3] = b1[1];
            }

            laca = __builtin_amdgcn_mfma_f32_16x16x16f16(aone, bpa, laca, 0, 0, 0);
            lacb = __builtin_amdgcn_mfma_f32_16x16x16f16(aone, bpb, lacb, 0, 0, 0);
#pragma unroll
            for (int dt = 0; dt < 4; ++dt) {
                const half4v av = *(const half4v*)(&Vl[buf][(nt * 4 + dt) * 256 + L * 4]);
                Oa[dt] = __builtin_amdgcn_mfma_f32_16x16x16f16(av, bpa, Oa[dt], 0, 0, 0);
                Ob[dt] = __builtin_amdgcn_mfma_f32_16x16x16f16(av, bpb, Ob[dt], 0, 0, 0);
            }
        }
    }

    // write unnormalized O-halves (fp16, K=32 granule: kappa=dd, mu=16*plane+c)
    const int ntile = qb * 4 + tl;
    half_t* dst = oh + (size_t)kh * 4194304 + (((size_t)bh * 64 + ntile) << 12);
#pragma unroll
    for (int dt = 0; dt < 4; ++dt) {
        const int obase = ((dt >> 1) * 4) * 512 + (((2 * dt + (g >> 1)) & 3) * 16 + c) * 8 + 4 * (g & 1);
        const half2v a0 = __builtin_bit_cast(half2v, __builtin_amdgcn_cvt_pkrtz(Oa[dt][0], Oa[dt][1]));
        const half2v a1 = __builtin_bit_cast(half2v, __builtin_amdgcn_cvt_pkrtz(Oa[dt][2], Oa[dt][3]));
        *(half2v*)(dst + obase + p0 * 512)     = a0;
        *(half2v*)(dst + obase + p0 * 512 + 2) = a1;
        const half2v b0 = __builtin_bit_cast(half2v, __builtin_amdgcn_cvt_pkrtz(Ob[dt][0], Ob[dt][1]));
        const half2v b1 = __builtin_bit_cast(half2v, __builtin_amdgcn_cvt_pkrtz(Ob[dt][2], Ob[dt][3]));
        *(half2v*)(dst + obase + p1 * 512)     = b0;
        *(half2v*)(dst + obase + p1 * 512 + 2) = b1;
    }
    // l: row m=0 of lac -> lanes 0..15, reg 0
    if (L < 16) {
        const size_t lb0 = (size_t)kh * 65536 + (size_t)bh * N_ + qb * 256 + 64 * tl;
        lbuf[lb0 + 16 * p0 + L] = laca[0];
        lbuf[lb0 + 16 * p1 + L] = lacb[0];
    }
}

// ---------------- GEMM3: out projection + split-K combine inline -------------
__global__ __launch_bounds__(256) void mm_out_mf(const half_t* __restrict__ woF,
                                                 const half_t* __restrict__ oh,
                                                 const float* __restrict__ lbuf,
                                                 float* __restrict__ out) {
    const int nt64 = blockIdx.x, mb = blockIdx.y, b = blockIdx.z;
    const int t = threadIdx.x, w = t >> 6, L = t & 63, c = L & 15, g = L >> 4;
    const int mt = mb * 4 + w;

    const half_t* Ab = woF + (size_t)mt * 8192;
    const floatx4 fz = {0.f, 0.f, 0.f, 0.f};
    floatx4 O4[4];
#pragma unroll
    for (int ns = 0; ns < 4; ++ns) O4[ns] = fz;

#pragma unroll
    for (int h = 0; h < 8; ++h) {
        const int bh = b * 8 + h;
        const size_t toff = (((size_t)bh * 64 + nt64) << 12);
        const half_t* B0 = oh + toff;
        const half_t* B1 = oh + 4194304 + toff;
        floatx4 acc[4];
#pragma unroll
        for (int ns = 0; ns < 4; ++ns) acc[ns] = fz;
#pragma unroll
        for (int c2 = 0; c2 < 2; ++c2) {
            const half8 af = *(const half8*)(Ab + (h * 8 + c2 * 4 + g) * 128 + c * 8);
#pragma unroll
            for (int ns = 0; ns < 4; ++ns) {
                const half8 b0 = *(const half8*)(B0 + (c2 * 4 + ns) * 512 + L * 8);
                const half8 b1 = *(const half8*)(B1 + (c2 * 4 + ns) * 512 + L * 8);
                const half8 s = b0 + b1;   // fixed-shift partials add directly
                acc[ns] = __builtin_amdgcn_mfma_f32_16x16x32_f16(af, s, acc[ns], 0, 0, 0);
            }
        }
#pragma unroll
        for (int ns = 0; ns < 4; ++ns) {
            const size_t li = (size_t)bh * N_ + nt64 * 64 + ns * 16 + c;
            const float l = lbuf[li] + lbuf[65536 + li];
            const float inv = __builtin_amdgcn_rcpf(l);
#pragma unroll
            for (int i = 0; i < 4; ++i) O4[ns][i] = fmaf(acc[ns][i], inv, O4[ns][i]);
        }
    }

    float* Cg = out + ((size_t)b * DIM_ + mt * 16) * N_ + nt64 * 64;
#pragma unroll
    for (int ns = 0; ns < 4; ++ns)
#pragma unroll
        for (int i = 0; i < 4; ++i)
            Cg[(size_t)(4 * g + i) * N_ + ns * 16 + c] = O4[ns][i];
}

extern "C" void kernel_launch(void* const* d_in, const int* in_sizes, int n_in,
                              void* d_out, int out_size, void* d_ws, size_t ws_size,
                              hipStream_t stream) {
    const float* fmap  = (const float*)d_in[0];
    const float* w_qkv = (const float*)d_in[1];
    const float* w_out = (const float*)d_in[2];
    float* out = (float*)d_out;

    char* ws = (char*)d_ws;
    half_t* perm = (half_t*)ws;                       // 25,165,824 B
    half_t* oh   = (half_t*)(ws + 25165824);          // 2 x 8,388,608 B
    float*  lbuf = (float*) (ws + 41943040);          // 2 x   262,144 B
    float*  sq   = (float*) (ws + 42467328);          //       524,288 B
    half_t* xTg  = (half_t*)(ws + 42991616);          //     4,194,304 B
    half_t* wqF  = (half_t*)(ws + 47185920);          //       786,432 B
    half_t* woF  = (half_t*)(ws + 47972352);          //       262,144 B

    prep_all <<<624, 256, 0, stream>>>(fmap, w_qkv, w_out, wqF, woF, xTg);
    mm_qkv_mf<<<dim3(64, 24, 2), 256, 0, stream>>>(wqF, xTg, perm, sq);
    attn_mfma<<<dim3(32, 8, 2), 512, 0, stream>>>(perm, sq, oh, lbuf);
    mm_out_mf<<<dim3(64, 4, 2), 256, 0, stream>>>(woF, oh, lbuf, out);
}

// Round 10
// 201.281 us; speedup vs baseline: 1.3268x; 1.0504x over previous
//
#include <hip/hip_runtime.h>

#define B_      2
#define DIM_    256
#define N_      4096
#define HEADS_  8
#define DINNER_ 512

typedef _Float16 half_t;
typedef _Float16 half8  __attribute__((ext_vector_type(8)));
typedef _Float16 half4v __attribute__((ext_vector_type(4)));
typedef _Float16 half2v __attribute__((ext_vector_type(2)));
typedef float    floatx4 __attribute__((ext_vector_type(4)));

#define SCL_    1.4426950408889634f  // log2(e), baked into Q,K
#define SHIFT2_ 20.0f                // fixed softmax shift (log2 domain)

// K=32 granule (64kappa x 64mu): halfoff(kappa,mu) =
//   ((kappa>>5)*4 + (mu>>4))*512 + (((kappa>>3)&3)*16 + (mu&15))*8 + (kappa&7)
// V tiles use the K=16 granule: off16(j,dd) =
//   ((j>>4)*4 + (dd>>4))*256 + (((j>>2)&3)*16 + (dd&15))*4 + (j&3)
// perm: [b][slab 0..23][ntile 0..63][4096 halfs]; slab<8: Q, <16: K, else V.
// xTg:  [b][ntile 0..63][kslab 0..3][4096 halfs]  (fmap in granule layout)

// ---------------- prep: weights -> A-frag fp16; fmap -> xTg granule fp16 -----
__global__ __launch_bounds__(256) void prep_all(const float* __restrict__ fmap,
                                                const float* __restrict__ w_qkv,
                                                const float* __restrict__ w_out,
                                                half_t* __restrict__ wqF,
                                                half_t* __restrict__ woF,
                                                half_t* __restrict__ xTg) {
    const int t = threadIdx.x, bx = blockIdx.x;
    __shared__ float Tl[64 * 68];
    if (bx < 96) {                 // w_qkv: 96 m-tiles x 256 k
        half_t* dst = wqF + (size_t)bx * 4096;
#pragma unroll
        for (int j = 0; j < 2; ++j) {
            const int cch = j * 256 + t;
            const int o = cch >> 4, m15 = cch & 15;
            const float4 a  = *(const float4*)&w_qkv[(size_t)(bx * 16 + m15) * 256 + o * 8];
            const float4 bb = *(const float4*)&w_qkv[(size_t)(bx * 16 + m15) * 256 + o * 8 + 4];
            half8 hv;
            hv[0] = (half_t)a.x;  hv[1] = (half_t)a.y;  hv[2] = (half_t)a.z;  hv[3] = (half_t)a.w;
            hv[4] = (half_t)bb.x; hv[5] = (half_t)bb.y; hv[6] = (half_t)bb.z; hv[7] = (half_t)bb.w;
            *(half8*)(dst + o * 128 + m15 * 8) = hv;
        }
    } else if (bx < 112) {         // w_out: 16 m-tiles x 512 k
        const int mt = bx - 96;
        half_t* dst = woF + (size_t)mt * 8192;
#pragma unroll
        for (int j = 0; j < 4; ++j) {
            const int cch = j * 256 + t;
            const int o = cch >> 4, m15 = cch & 15;
            const float4 a  = *(const float4*)&w_out[(size_t)(mt * 16 + m15) * 512 + o * 8];
            const float4 bb = *(const float4*)&w_out[(size_t)(mt * 16 + m15) * 512 + o * 8 + 4];
            half8 hv;
            hv[0] = (half_t)a.x;  hv[1] = (half_t)a.y;  hv[2] = (half_t)a.z;  hv[3] = (half_t)a.w;
            hv[4] = (half_t)bb.x; hv[5] = (half_t)bb.y; hv[6] = (half_t)bb.z; hv[7] = (half_t)bb.w;
            *(half8*)(dst + o * 128 + m15 * 8) = hv;
        }
    } else {                       // fmap [k][n] fp32 -> xTg granule fp16
        const int idx = bx - 112;
        const int n0 = (idx & 63) * 64, k0 = ((idx >> 6) & 3) * 64, b = idx >> 8;
        {
            const int kk = t >> 2, nq = (t & 3) * 16;
#pragma unroll
            for (int q = 0; q < 4; ++q) {
                float4 v = *(const float4*)&fmap[((size_t)b * DIM_ + k0 + kk) * N_ + n0 + nq + 4 * q];
                *(float4*)&Tl[kk * 68 + nq + 4 * q] = v;
            }
        }
        __syncthreads();
        {
            const int n = t >> 2, ko = (t & 3) * 16;   // kappa_local = ko..ko+15
            half8 h0, h1;
#pragma unroll
            for (int j = 0; j < 8; ++j) h0[j] = (half_t)Tl[(ko + j) * 68 + n];
#pragma unroll
            for (int j = 0; j < 8; ++j) h1[j] = (half_t)Tl[(ko + 8 + j) * 68 + n];
            half_t* dst = xTg + (((size_t)b * 64 + (n0 >> 6)) * 4 + (k0 >> 6)) * 4096;
            const int o0 = ((ko >> 5) * 4 + (n >> 4)) * 512 + (((ko >> 3) & 3) * 16 + (n & 15)) * 8;
            const int k8 = ko + 8;
            const int o1 = ((k8 >> 5) * 4 + (n >> 4)) * 512 + (((k8 >> 3) & 3) * 16 + (n & 15)) * 8;
            *(half8*)(dst + o0) = h0;
            *(half8*)(dst + o1) = h1;
        }
    }
}

// ---------------- GEMM1: qkv projection + fused sq; coalesced LDS-bounce -----
__global__ __launch_bounds__(256) void mm_qkv_mf(const half_t* __restrict__ wqF,
                                                 const half_t* __restrict__ xTg,
                                                 half_t* __restrict__ perm,
                                                 float* __restrict__ sq) {
    const int nt64 = blockIdx.x, by = blockIdx.y, b = blockIdx.z;
    const int t = threadIdx.x, w = t >> 6, L = t & 63, c = L & 15, g = L >> 4;
    const int mt = by * 4 + w;

    const half_t* Ab = wqF + (size_t)mt * 4096;
    const half_t* Bb = xTg + (((size_t)b * 64 + nt64) * 4) * 4096;

    __shared__ __align__(16) char smraw[8192 + 4352];
    half_t* VtH = (half_t*)smraw;                 // 4096-half granule bounce
    float*  red = (float*)(smraw + 8192);         // sq reduction, stride 17

    const floatx4 fz = {0.f, 0.f, 0.f, 0.f};
    floatx4 acc[4];
#pragma unroll
    for (int ns = 0; ns < 4; ++ns) acc[ns] = fz;

#pragma unroll
    for (int kc = 0; kc < 8; ++kc) {
        const half8 af = *(const half8*)(Ab + (kc * 4 + g) * 128 + c * 8);
        const half_t* Bs = Bb + (kc >> 1) * 4096 + (kc & 1) * 2048;
#pragma unroll
        for (int ns = 0; ns < 4; ++ns) {
            const half8 bf = *(const half8*)(Bs + ns * 512 + L * 8);   // linear, coalesced
            acc[ns] = __builtin_amdgcn_mfma_f32_16x16x32_f16(af, bf, acc[ns], 0, 0, 0);
        }
    }

    half_t* dst = perm + (((size_t)(b * 24 + by) * 64 + nt64) << 12);
    if (by < 16) {
        // Q/K scaled by log2e: kappa = d = 16w+4g+i, mu = 16ns+c.
        float part[4];
#pragma unroll
        for (int ns = 0; ns < 4; ++ns) {
            half_t hv[4];
            float s = 0.f;
#pragma unroll
            for (int i = 0; i < 4; ++i) {
                hv[i] = (half_t)(acc[ns][i] * SCL_);
                const float f = (float)hv[i];
                s = fmaf(f, f, s);
            }
            part[ns] = s;
            const int off = ((w >> 1) * 4 + ns) * 512 + (((2 * w + (g >> 1)) & 3) * 16 + c) * 8 + 4 * (g & 1);
            half2v p0, p1;
            p0[0] = hv[0]; p0[1] = hv[1];
            p1[0] = hv[2]; p1[1] = hv[3];
            *(half2v*)(VtH + off)     = p0;
            *(half2v*)(VtH + off + 2) = p1;
        }
#pragma unroll
        for (int ns = 0; ns < 4; ++ns)
            red[(ns * 16 + (w * 4 + g)) * 17 + c] = part[ns];
        __syncthreads();
#pragma unroll
        for (int j = 0; j < 2; ++j)
            *(half8*)(dst + t * 16 + j * 8) = *(half8*)(VtH + t * 16 + j * 8);
        if (t < 64) {
            const int ns = t >> 4, cc = t & 15;
            float s = 0.f;
#pragma unroll
            for (int wg = 0; wg < 16; ++wg) s += red[(ns * 16 + wg) * 17 + cc];
            const int tens = by >> 3, hh = by & 7;
            sq[((size_t)(tens * 16 + b * 8 + hh)) * N_ + nt64 * 64 + ns * 16 + cc] = s;
        }
    } else {
        // V: j = 16ns+c (spatial), dd = 16w+4g+i -> K=16 granule via LDS bounce
#pragma unroll
        for (int ns = 0; ns < 4; ++ns)
#pragma unroll
            for (int i = 0; i < 4; ++i)
                VtH[(ns * 4 + w) * 256 + ((c >> 2) * 16 + 4 * g + i) * 4 + (c & 3)] = (half_t)acc[ns][i];
        __syncthreads();
#pragma unroll
        for (int j = 0; j < 2; ++j)
            *(half8*)(dst + t * 16 + j * 8) = *(half8*)(VtH + t * 16 + j * 8);
    }
}

// ---------------- fused distance-attention, split-K x4, no-drain pipeline ----
// grid.x = 64: qb = bx&15 (256 queries), kh = bx>>4 (K-quarters). 1024 blocks
// -> 4 blocks/CU (LDS 36 KB), 32 waves/CU. Single lgkm-only barrier per iter;
// K/V prefetch after the barrier overlaps compute. Fixed-shift softmax ->
// partials add with no rescale (combined inline in mm_out).
__global__ __launch_bounds__(512) void attn_mfma(const half_t* __restrict__ perm,
                                                 const float* __restrict__ sq,
                                                 half_t* __restrict__ oh,
                                                 float* __restrict__ lbuf) {
    const int bx = blockIdx.x;
    const int qb = bx & 15, kh = bx >> 4;
    const int h = blockIdx.y, b = blockIdx.z;
    const int bh = b * HEADS_ + h;

    const half_t* Qb = perm + ((size_t)(b * 24 + h) << 18);
    const half_t* Kb = perm + ((size_t)(b * 24 + 8 + h) << 18);
    const half_t* Vb = perm + ((size_t)(b * 24 + 16 + h) << 18);
    const float* q2a = sq + (size_t)bh * N_;
    const float* k2a = sq + (size_t)(16 + bh) * N_;

    __shared__ __align__(16) half_t Kl[2][4096];
    __shared__ __align__(16) half_t Vl[2][4096];
    __shared__ __align__(16) float  k2l[1024];

    const int t = threadIdx.x, w = t >> 6, L = t & 63, c = L & 15, g = L >> 4;
    const floatx4 fz = {0.f, 0.f, 0.f, 0.f};

    // stage this K-quarter's k2 (4 KB) once; visible after iter-0 barrier
    *(float2*)&k2l[t * 2] = *(const float2*)&k2a[kh * 1024 + t * 2];

    // persistent Q B-frags for 2 subtiles
    const int tl = w >> 1;
    const int p0 = (w & 1) * 2, p1 = p0 + 1;
    const half_t* Qt = Qb + ((size_t)(qb * 4 + tl) << 12);
    const half8 bq0a = *(const half8*)(Qt + (0 * 4 + p0) * 512 + L * 8);
    const half8 bq1a = *(const half8*)(Qt + (1 * 4 + p0) * 512 + L * 8);
    const half8 bq0b = *(const half8*)(Qt + (0 * 4 + p1) * 512 + L * 8);
    const half8 bq1b = *(const half8*)(Qt + (1 * 4 + p1) * 512 + L * 8);
    const float q2la = q2a[qb * 256 + 64 * tl + 16 * p0 + c];
    const float q2lb = q2a[qb * 256 + 64 * tl + 16 * p1 + c];

    half4v aone;   // ones row m=0 for l-MFMA
    {
        const half_t ov = (c == 0) ? (half_t)1.0f : (half_t)0.0f;
        aone[0] = ov; aone[1] = ov; aone[2] = ov; aone[3] = ov;
    }

    floatx4 Oa[4], Ob[4];
    floatx4 laca = fz, lacb = fz;
#pragma unroll
    for (int dt = 0; dt < 4; ++dt) { Oa[dt] = fz; Ob[dt] = fz; }

    const int kt0 = kh * 16;
    half8 rk = *(const half8*)(Kb + ((size_t)kt0 << 12) + t * 8);
    half8 rv = *(const half8*)(Vb + ((size_t)kt0 << 12) + t * 8);

    for (int it = 0; it < 16; ++it) {
        const int buf = it & 1;
        *(half8*)(&Kl[buf][t * 8]) = rk;     // waits vmcnt for rk/rv data dep only
        *(half8*)(&Vl[buf][t * 8]) = rv;
        // LDS-only barrier: vmcnt (prefetch) stays outstanding across it.
        asm volatile("s_waitcnt lgkmcnt(0)\n\ts_barrier" ::: "memory");
        if (it < 15) {                        // prefetch overlaps compute below
            rk = *(const half8*)(Kb + ((size_t)(kt0 + it + 1) << 12) + t * 8);
            rv = *(const half8*)(Vb + ((size_t)(kt0 + it + 1) << 12) + t * 8);
        }

#pragma unroll
        for (int nt = 0; nt < 4; ++nt) {
            const half8 ak0 = *(const half8*)(&Kl[buf][(0 * 4 + nt) * 512 + L * 8]);
            const half8 ak1 = *(const half8*)(&Kl[buf][(1 * 4 + nt) * 512 + L * 8]);
            floatx4 Sa = __builtin_amdgcn_mfma_f32_16x16x32_f16(ak0, bq0a, fz, 0, 0, 0);
            Sa = __builtin_amdgcn_mfma_f32_16x16x32_f16(ak1, bq1a, Sa, 0, 0, 0);
            floatx4 Sb = __builtin_amdgcn_mfma_f32_16x16x32_f16(ak0, bq0b, fz, 0, 0, 0);
            Sb = __builtin_amdgcn_mfma_f32_16x16x32_f16(ak1, bq1b, Sb, 0, 0, 0);
            const float4 k2v = *(const float4*)&k2l[it * 64 + 16 * nt + 4 * g];

            float pa[4], pb[4];
            const float k2arr[4] = {k2v.x, k2v.y, k2v.z, k2v.w};
#pragma unroll
            for (int i = 0; i < 4; ++i) {
                // |d2| instead of max(d2,0): abs is a free src modifier on sqrt
                pa[i] = __builtin_amdgcn_exp2f(
                    __builtin_amdgcn_sqrtf(__builtin_fabsf(fmaf(Sa[i], -2.0f, q2la + k2arr[i]))) - SHIFT2_);
                pb[i] = __builtin_amdgcn_exp2f(
                    __builtin_amdgcn_sqrtf(__builtin_fabsf(fmaf(Sb[i], -2.0f, q2lb + k2arr[i]))) - SHIFT2_);
            }
            half4v bpa, bpb;
            {
                const half2v a0 = __builtin_bit_cast(half2v, __builtin_amdgcn_cvt_pkrtz(pa[0], pa[1]));
                const half2v a1 = __builtin_bit_cast(half2v, __builtin_amdgcn_cvt_pkrtz(pa[2], pa[3]));
                bpa[0] = a0[0]; bpa[1] = a0[1]; bpa[2] = a1[0]; bpa[3] = a1[1];
                const half2v b0 = __builtin_bit_cast(half2v, __builtin_amdgcn_cvt_pkrtz(pb[0], pb[1]));
                const half2v b1 = __builtin_bit_cast(half2v, __builtin_amdgcn_cvt_pkrtz(pb[2], pb[3]));
                bpb[0] = b0[0]; bpb[1] = b0[1]; bpb[2] = b1[0]; bpb[3] = b1[1];
            }

            laca = __builtin_amdgcn_mfma_f32_16x16x16f16(aone, bpa, laca, 0, 0, 0);
            lacb = __builtin_amdgcn_mfma_f32_16x16x16f16(aone, bpb, lacb, 0, 0, 0);
#pragma unroll
            for (int dt = 0; dt < 4; ++dt) {
                const half4v av = *(const half4v*)(&Vl[buf][(nt * 4 + dt) * 256 + L * 4]);
                Oa[dt] = __builtin_amdgcn_mfma_f32_16x16x16f16(av, bpa, Oa[dt], 0, 0, 0);
                Ob[dt] = __builtin_amdgcn_mfma_f32_16x16x16f16(av, bpb, Ob[dt], 0, 0, 0);
            }
        }
    }

    // write unnormalized O-quarters (fp16, K=32 granule: kappa=dd, mu=16*plane+c)
    const int ntile = qb * 4 + tl;
    half_t* dst = oh + (size_t)kh * 4194304 + (((size_t)bh * 64 + ntile) << 12);
#pragma unroll
    for (int dt = 0; dt < 4; ++dt) {
        const int obase = ((dt >> 1) * 4) * 512 + (((2 * dt + (g >> 1)) & 3) * 16 + c) * 8 + 4 * (g & 1);
        const half2v a0 = __builtin_bit_cast(half2v, __builtin_amdgcn_cvt_pkrtz(Oa[dt][0], Oa[dt][1]));
        const half2v a1 = __builtin_bit_cast(half2v, __builtin_amdgcn_cvt_pkrtz(Oa[dt][2], Oa[dt][3]));
        *(half2v*)(dst + obase + p0 * 512)     = a0;
        *(half2v*)(dst + obase + p0 * 512 + 2) = a1;
        const half2v b0 = __builtin_bit_cast(half2v, __builtin_amdgcn_cvt_pkrtz(Ob[dt][0], Ob[dt][1]));
        const half2v b1 = __builtin_bit_cast(half2v, __builtin_amdgcn_cvt_pkrtz(Ob[dt][2], Ob[dt][3]));
        *(half2v*)(dst + obase + p1 * 512)     = b0;
        *(half2v*)(dst + obase + p1 * 512 + 2) = b1;
    }
    // l: row m=0 of lac -> lanes 0..15, reg 0
    if (L < 16) {
        const size_t lb0 = (size_t)kh * 65536 + (size_t)bh * N_ + qb * 256 + 64 * tl;
        lbuf[lb0 + 16 * p0 + L] = laca[0];
        lbuf[lb0 + 16 * p1 + L] = lacb[0];
    }
}

// ---------------- GEMM3: out projection + split-K x4 combine inline ----------
__global__ __launch_bounds__(256) void mm_out_mf(const half_t* __restrict__ woF,
                                                 const half_t* __restrict__ oh,
                                                 const float* __restrict__ lbuf,
                                                 float* __restrict__ out) {
    const int nt64 = blockIdx.x, mb = blockIdx.y, b = blockIdx.z;
    const int t = threadIdx.x, w = t >> 6, L = t & 63, c = L & 15, g = L >> 4;
    const int mt = mb * 4 + w;

    const half_t* Ab = woF + (size_t)mt * 8192;
    const floatx4 fz = {0.f, 0.f, 0.f, 0.f};
    floatx4 O4[4];
#pragma unroll
    for (int ns = 0; ns < 4; ++ns) O4[ns] = fz;

#pragma unroll
    for (int h = 0; h < 8; ++h) {
        const int bh = b * 8 + h;
        const size_t toff = (((size_t)bh * 64 + nt64) << 12);
        const half_t* B0 = oh + toff;
        const half_t* B1 = oh + 4194304 + toff;
        const half_t* B2 = oh + 2 * 4194304 + toff;
        const half_t* B3 = oh + 3 * 4194304 + toff;
        floatx4 acc[4];
#pragma unroll
        for (int ns = 0; ns < 4; ++ns) acc[ns] = fz;
#pragma unroll
        for (int c2 = 0; c2 < 2; ++c2) {
            const half8 af = *(const half8*)(Ab + (h * 8 + c2 * 4 + g) * 128 + c * 8);
#pragma unroll
            for (int ns = 0; ns < 4; ++ns) {
                const int boff = (c2 * 4 + ns) * 512 + L * 8;
                const half8 b0 = *(const half8*)(B0 + boff);
                const half8 b1 = *(const half8*)(B1 + boff);
                const half8 b2 = *(const half8*)(B2 + boff);
                const half8 b3 = *(const half8*)(B3 + boff);
                const half8 s = (b0 + b1) + (b2 + b3);   // fixed-shift partials add
                acc[ns] = __builtin_amdgcn_mfma_f32_16x16x32_f16(af, s, acc[ns], 0, 0, 0);
            }
        }
#pragma unroll
        for (int ns = 0; ns < 4; ++ns) {
            const size_t li = (size_t)bh * N_ + nt64 * 64 + ns * 16 + c;
            const float l = (lbuf[li] + lbuf[65536 + li]) +
                            (lbuf[2 * 65536 + li] + lbuf[3 * 65536 + li]);
            const float inv = __builtin_amdgcn_rcpf(l);
#pragma unroll
            for (int i = 0; i < 4; ++i) O4[ns][i] = fmaf(acc[ns][i], inv, O4[ns][i]);
        }
    }

    float* Cg = out + ((size_t)b * DIM_ + mt * 16) * N_ + nt64 * 64;
#pragma unroll
    for (int ns = 0; ns < 4; ++ns)
#pragma unroll
        for (int i = 0; i < 4; ++i)
            Cg[(size_t)(4 * g + i) * N_ + ns * 16 + c] = O4[ns][i];
}

extern "C" void kernel_launch(void* const* d_in, const int* in_sizes, int n_in,
                              void* d_out, int out_size, void* d_ws, size_t ws_size,
                              hipStream_t stream) {
    const float* fmap  = (const float*)d_in[0];
    const float* w_qkv = (const float*)d_in[1];
    const float* w_out = (const float*)d_in[2];
    float* out = (float*)d_out;

    char* ws = (char*)d_ws;
    // Overlay plan: xTg and wqF are dead after mm_qkv; attn's oh overlays them.
    half_t* perm = (half_t*)ws;                       // 25,165,824 B
    float*  sq   = (float*) (ws + 25165824);          //    524,288 B
    float*  lbuf = (float*) (ws + 25690112);          // 4 x 262,144 B
    half_t* woF  = (half_t*)(ws + 26738688);          //    262,144 B (read by mm_out)
    half_t* oh   = (half_t*)(ws + 27000832);          // 4 x 8,388,608 B (after mm_qkv)
    half_t* xTg  = (half_t*)(ws + 27000832);          //  4,194,304 B (aliases oh)
    half_t* wqF  = (half_t*)(ws + 31195136);          //    786,432 B (aliases oh)

    prep_all <<<624, 256, 0, stream>>>(fmap, w_qkv, w_out, wqF, woF, xTg);
    mm_qkv_mf<<<dim3(64, 24, 2), 256, 0, stream>>>(wqF, xTg, perm, sq);
    attn_mfma<<<dim3(64, 8, 2), 512, 0, stream>>>(perm, sq, oh, lbuf);
    mm_out_mf<<<dim3(64, 4, 2), 256, 0, stream>>>(woF, oh, lbuf, out);
}